// Round 2
// baseline (1952.527 us; speedup 1.0000x reference)
//
#include <hip/hip_runtime.h>
#include <hip/hip_bf16.h>

// monotone float <-> uint encoding for atomicMax on floats (incl. negatives)
__device__ __forceinline__ unsigned fenc(float f) {
    unsigned u = __float_as_uint(f);
    return (u & 0x80000000u) ? ~u : (u | 0x80000000u);
}
__device__ __forceinline__ float fdec(unsigned u) {
    return (u & 0x80000000u) ? __uint_as_float(u & 0x7fffffffu) : __uint_as_float(~u);
}

__device__ __forceinline__ float lrelu02(float v) { return v > 0.f ? v : 0.2f * v; }

// ---------- layer-1 dense: h1 = x @ W1  (+ fused per-head attn dots) ----------
__global__ __launch_bounds__(256) void gemm1_k(
    const float* __restrict__ x, const float* __restrict__ W1,
    const float* __restrict__ aw_s, const float* __restrict__ aw_d,
    float* __restrict__ h1, float* __restrict__ as1, float* __restrict__ ad1, int N)
{
    __shared__ float Wl[128 * 128];   // 64 KB
    __shared__ float xs[2][128];
    for (int i = threadIdx.x; i < 128 * 128; i += 256) Wl[i] = W1[i];
    const int local = threadIdx.x >> 7;      // 0/1: which of the 2 rows
    const int j = threadIdx.x & 127;         // output column = head*32 + c
    const float ws_ = aw_s[j];
    const float wd_ = aw_d[j];
    for (int base = blockIdx.x * 2; base < N; base += gridDim.x * 2) {
        const int n = base + local;
        __syncthreads();
        xs[local][j] = (n < N) ? x[(size_t)n * 128 + j] : 0.f;
        __syncthreads();
        float acc = 0.f;
        #pragma unroll
        for (int k = 0; k < 128; ++k) acc += xs[local][k] * Wl[k * 128 + j];
        if (n < N) {
            h1[(size_t)n * 128 + j] = acc;
            float s = acc * ws_, d = acc * wd_;
            #pragma unroll
            for (int off = 16; off; off >>= 1) {
                s += __shfl_down(s, off, 32);
                d += __shfl_down(d, off, 32);
            }
            if ((j & 31) == 0) { int hh = j >> 5; as1[n * 4 + hh] = s; ad1[n * 4 + hh] = d; }
        }
    }
}

// ---------- edge pass 1: segment max over dst ----------
template<int H>
__global__ __launch_bounds__(256) void edge_max_k(
    const int* __restrict__ ei, int E, int N,
    const float* __restrict__ as_, const float* __restrict__ ad_,
    unsigned* __restrict__ mEnc)
{
    int e = blockIdx.x * 256 + threadIdx.x;
    int total = E + N;
    if (e >= total) return;
    int s, d;
    if (e < E) { s = ei[e]; d = ei[E + e]; } else { s = d = e - E; }
    #pragma unroll
    for (int h = 0; h < H; ++h) {
        float v = lrelu02(as_[s * H + h] + ad_[d * H + h]);
        atomicMax(&mEnc[d * H + h], fenc(v));
    }
}

// ---------- edge pass 2: segment sum of exp(e - m) ----------
template<int H>
__global__ __launch_bounds__(256) void edge_sum_k(
    const int* __restrict__ ei, int E, int N,
    const float* __restrict__ as_, const float* __restrict__ ad_,
    const unsigned* __restrict__ mEnc, float* __restrict__ denom)
{
    int e = blockIdx.x * 256 + threadIdx.x;
    int total = E + N;
    if (e >= total) return;
    int s, d;
    if (e < E) { s = ei[e]; d = ei[E + e]; } else { s = d = e - E; }
    #pragma unroll
    for (int h = 0; h < H; ++h) {
        float v = lrelu02(as_[s * H + h] + ad_[d * H + h]);
        atomicAdd(&denom[d * H + h], __expf(v - fdec(mEnc[d * H + h])));
    }
}

// ---------- layer-1 scatter: out1[dst] += h1[src] * alpha  (128 ch/edge) ----------
__global__ __launch_bounds__(256) void scatter1_k(
    const int* __restrict__ ei, int E, int N,
    const float* __restrict__ as_, const float* __restrict__ ad_,
    const unsigned* __restrict__ mEnc, const float* __restrict__ denom,
    const float* __restrict__ h1, float* __restrict__ out1)
{
    int idx = blockIdx.x * 256 + threadIdx.x;
    int e = idx >> 7, j = idx & 127;
    int total = E + N;
    if (e >= total) return;
    int s, d;
    if (e < E) { s = ei[e]; d = ei[E + e]; } else { s = d = e - E; }
    int h = j >> 5;
    float v = lrelu02(as_[s * 4 + h] + ad_[d * 4 + h]);
    float ex = __expf(v - fdec(mEnc[d * 4 + h]));
    float alpha = ex / (denom[d * 4 + h] + 1e-16f);
    atomicAdd(&out1[(size_t)d * 128 + j], h1[(size_t)s * 128 + j] * alpha);
}

// ---------- bias + ELU (in place) ----------
__global__ __launch_bounds__(256) void bias_elu_k(
    float* __restrict__ buf, const float* __restrict__ bias, int count, int mask)
{
    int idx = blockIdx.x * 256 + threadIdx.x;
    if (idx >= count) return;
    float v = buf[idx] + bias[idx & mask];
    buf[idx] = v > 0.f ? v : expm1f(v);
}

// ---------- layer-2 dense: g = h2 @ W2 (+ attn dots), H=1 C=8 ----------
__global__ __launch_bounds__(256) void gemm2_k(
    const float* __restrict__ h2, const float* __restrict__ W2,
    const float* __restrict__ aw_s, const float* __restrict__ aw_d,
    float* __restrict__ g, float* __restrict__ as2, float* __restrict__ ad2, int N)
{
    __shared__ float W2l[128 * 8];
    __shared__ float rows[32][129];   // +1 pad: kills 8-way bank conflict
    for (int i = threadIdx.x; i < 128 * 8; i += 256) W2l[i] = W2[i];
    const int r = threadIdx.x >> 3, j = threadIdx.x & 7;
    const float ws_ = aw_s[j], wd_ = aw_d[j];
    for (int base = blockIdx.x * 32; base < N; base += gridDim.x * 32) {
        __syncthreads();
        for (int i = threadIdx.x; i < 32 * 128; i += 256) {
            int rr = i >> 7, k = i & 127;
            int n = base + rr;
            rows[rr][k] = (n < N) ? h2[(size_t)n * 128 + k] : 0.f;
        }
        __syncthreads();
        int n = base + r;
        float acc = 0.f;
        #pragma unroll
        for (int k = 0; k < 128; ++k) acc += rows[r][k] * W2l[k * 8 + j];
        if (n < N) {
            g[n * 8 + j] = acc;
            float s = acc * ws_, d = acc * wd_;
            #pragma unroll
            for (int off = 4; off; off >>= 1) {
                s += __shfl_down(s, off, 8);
                d += __shfl_down(d, off, 8);
            }
            if (j == 0) { as2[n] = s; ad2[n] = d; }
        }
    }
}

// ---------- layer-2 scatter: out2[dst] += g[src] * alpha (8 ch/edge) ----------
__global__ __launch_bounds__(256) void scatter2_k(
    const int* __restrict__ ei, int E, int N,
    const float* __restrict__ as_, const float* __restrict__ ad_,
    const unsigned* __restrict__ mEnc, const float* __restrict__ denom,
    const float* __restrict__ g, float* __restrict__ out2)
{
    int idx = blockIdx.x * 256 + threadIdx.x;
    int e = idx >> 3, j = idx & 7;
    int total = E + N;
    if (e >= total) return;
    int s, d;
    if (e < E) { s = ei[e]; d = ei[E + e]; } else { s = d = e - E; }
    float v = lrelu02(as_[s] + ad_[d]);
    float ex = __expf(v - fdec(mEnc[d]));
    float alpha = ex / (denom[d] + 1e-16f);
    atomicAdd(&out2[d * 8 + j], g[s * 8 + j] * alpha);
}

// ---------- epilogue: sigmoid(elu(out2 + b2) @ Wlin + blin) ----------
__global__ __launch_bounds__(256) void final_k(
    const float* __restrict__ out2, const float* __restrict__ b2_,
    const float* __restrict__ Wlin, const float* __restrict__ blin,
    float* __restrict__ out, int N)
{
    int n = blockIdx.x * 256 + threadIdx.x;
    if (n >= N) return;
    float acc = blin[0];
    #pragma unroll
    for (int j = 0; j < 8; ++j) {
        float v = out2[n * 8 + j] + b2_[j];
        v = v > 0.f ? v : expm1f(v);
        acc += v * Wlin[j];
    }
    out[n] = 1.f / (1.f + __expf(-acc));
}

extern "C" void kernel_launch(void* const* d_in, const int* in_sizes, int n_in,
                              void* d_out, int out_size, void* d_ws, size_t ws_size,
                              hipStream_t stream)
{
    (void)n_in; (void)out_size; (void)ws_size;
    const float* x    = (const float*)d_in[0];
    const int*   ei   = (const int*)d_in[1];
    // d_in[2] = edge_attr, ignored (edge_dim=None)
    const float* W1   = (const float*)d_in[3];
    const float* as1w = (const float*)d_in[4];
    const float* ad1w = (const float*)d_in[5];
    const float* b1   = (const float*)d_in[6];
    const float* W2   = (const float*)d_in[7];
    const float* as2w = (const float*)d_in[8];
    const float* ad2w = (const float*)d_in[9];
    const float* b2v  = (const float*)d_in[10];
    const float* Wlin = (const float*)d_in[11];
    const float* blin = (const float*)d_in[12];

    const int N = in_sizes[0] / 128;
    const int E = in_sizes[1] / 2;
    const int total = E + N;

    // workspace layout (fp32 elements); ~117 MB total
    float* p = (float*)d_ws;
    float* h1  = p; p += (size_t)N * 128;
    float* as1 = p; p += (size_t)N * 4;
    float* ad1 = p; p += (size_t)N * 4;
    float* g   = p; p += (size_t)N * 8;
    float* as2 = p; p += (size_t)N;
    float* ad2 = p; p += (size_t)N;
    // zero-initialized region (single memset)
    float* zbase = p;
    unsigned* m1 = (unsigned*)p; p += (size_t)N * 4;
    float* den1  = p; p += (size_t)N * 4;
    float* out1  = p; p += (size_t)N * 128;
    unsigned* m2 = (unsigned*)p; p += (size_t)N;
    float* den2  = p; p += (size_t)N;
    float* out2  = p; p += (size_t)N * 8;
    size_t zbytes = (size_t)(p - zbase) * sizeof(float);
    hipMemsetAsync(zbase, 0, zbytes, stream);

    // layer 1
    gemm1_k<<<2048, 256, 0, stream>>>(x, W1, as1w, ad1w, h1, as1, ad1, N);
    int eb = (total + 255) / 256;
    edge_max_k<4><<<eb, 256, 0, stream>>>(ei, E, N, as1, ad1, m1);
    edge_sum_k<4><<<eb, 256, 0, stream>>>(ei, E, N, as1, ad1, m1, den1);
    long long t1 = (long long)total * 128;
    scatter1_k<<<(int)((t1 + 255) / 256), 256, 0, stream>>>(ei, E, N, as1, ad1, m1, den1, h1, out1);
    int nb1 = (int)(((long long)N * 128 + 255) / 256);
    bias_elu_k<<<nb1, 256, 0, stream>>>(out1, b1, N * 128, 127);

    // layer 2
    gemm2_k<<<3125, 256, 0, stream>>>(out1, W2, as2w, ad2w, g, as2, ad2, N);
    edge_max_k<1><<<eb, 256, 0, stream>>>(ei, E, N, as2, ad2, m2);
    edge_sum_k<1><<<eb, 256, 0, stream>>>(ei, E, N, as2, ad2, m2, den2);
    long long t2 = (long long)total * 8;
    scatter2_k<<<(int)((t2 + 255) / 256), 256, 0, stream>>>(ei, E, N, as2, ad2, m2, den2, g, out2);

    // epilogue
    final_k<<<(N + 255) / 256, 256, 0, stream>>>(out2, b2v, Wlin, blin, (float*)d_out, N);
}

// Round 3
// 832.622 us; speedup vs baseline: 2.3450x; 2.3450x over previous
//
#include <hip/hip_runtime.h>
#include <hip/hip_bf16.h>

__device__ __forceinline__ float lrelu02(float v) { return v > 0.f ? v : 0.2f * v; }

// ---------- layer-1 dense: h1 = x @ W1  (+ fused per-head attn dots) ----------
__global__ __launch_bounds__(256) void gemm1_k(
    const float* __restrict__ x, const float* __restrict__ W1,
    const float* __restrict__ aw_s, const float* __restrict__ aw_d,
    float* __restrict__ h1, float* __restrict__ as1, float* __restrict__ ad1, int N)
{
    __shared__ float Wl[128 * 128];   // 64 KB
    __shared__ float xs[2][128];
    for (int i = threadIdx.x; i < 128 * 128; i += 256) Wl[i] = W1[i];
    const int local = threadIdx.x >> 7;
    const int j = threadIdx.x & 127;
    const float ws_ = aw_s[j];
    const float wd_ = aw_d[j];
    for (int base = blockIdx.x * 2; base < N; base += gridDim.x * 2) {
        const int n = base + local;
        __syncthreads();
        xs[local][j] = (n < N) ? x[(size_t)n * 128 + j] : 0.f;
        __syncthreads();
        float acc = 0.f;
        #pragma unroll
        for (int k = 0; k < 128; ++k) acc += xs[local][k] * Wl[k * 128 + j];
        if (n < N) {
            h1[(size_t)n * 128 + j] = acc;
            float s = acc * ws_, d = acc * wd_;
            #pragma unroll
            for (int off = 16; off; off >>= 1) {
                s += __shfl_down(s, off, 32);
                d += __shfl_down(d, off, 32);
            }
            if ((j & 31) == 0) { int hh = j >> 5; as1[n * 4 + hh] = s; ad1[n * 4 + hh] = d; }
        }
    }
}

// ---------- CSR build ----------
__global__ __launch_bounds__(256) void degcnt_k(
    const int* __restrict__ ei, int E, int N, int* __restrict__ deg)
{
    int e = blockIdx.x * 256 + threadIdx.x;
    if (e >= E + N) return;
    int d = (e < E) ? ei[E + e] : (e - E);
    atomicAdd(&deg[d], 1);
}

__global__ __launch_bounds__(256) void blocksum_k(
    const int* __restrict__ deg, int N, int* __restrict__ bsum)
{
    __shared__ int sh[256];
    int i = blockIdx.x * 256 + threadIdx.x;
    sh[threadIdx.x] = (i < N) ? deg[i] : 0;
    __syncthreads();
    for (int off = 128; off; off >>= 1) {
        if (threadIdx.x < off) sh[threadIdx.x] += sh[threadIdx.x + off];
        __syncthreads();
    }
    if (threadIdx.x == 0) bsum[blockIdx.x] = sh[0];
}

__global__ __launch_bounds__(1024) void scanbsum_k(int* __restrict__ bsum, int nb)
{
    __shared__ int buf[1024];
    __shared__ int carry;
    if (threadIdx.x == 0) carry = 0;
    __syncthreads();
    for (int base = 0; base < nb; base += 1024) {
        int i = base + threadIdx.x;
        int v = (i < nb) ? bsum[i] : 0;
        buf[threadIdx.x] = v;
        __syncthreads();
        for (int off = 1; off < 1024; off <<= 1) {
            int t = (threadIdx.x >= off) ? buf[threadIdx.x - off] : 0;
            __syncthreads();
            buf[threadIdx.x] += t;
            __syncthreads();
        }
        if (i < nb) bsum[i] = buf[threadIdx.x] - v + carry;   // exclusive
        __syncthreads();
        if (threadIdx.x == 0) carry += buf[1023];
        __syncthreads();
    }
}

__global__ __launch_bounds__(256) void rowptr_k(
    const int* __restrict__ deg, const int* __restrict__ bsum, int N, int E,
    int* __restrict__ rowptr, int* __restrict__ cursor)
{
    __shared__ int buf[256];
    int i = blockIdx.x * 256 + threadIdx.x;
    int v = (i < N) ? deg[i] : 0;
    buf[threadIdx.x] = v;
    __syncthreads();
    for (int off = 1; off < 256; off <<= 1) {
        int t = (threadIdx.x >= off) ? buf[threadIdx.x - off] : 0;
        __syncthreads();
        buf[threadIdx.x] += t;
        __syncthreads();
    }
    if (i < N) {
        int excl = bsum[blockIdx.x] + buf[threadIdx.x] - v;
        rowptr[i] = excl;
        cursor[i] = excl;
    }
    if (i == 0) rowptr[N] = E + N;
}

__global__ __launch_bounds__(256) void fill_k(
    const int* __restrict__ ei, int E, int N,
    int* __restrict__ cursor, int* __restrict__ csr)
{
    int e = blockIdx.x * 256 + threadIdx.x;
    if (e >= E + N) return;
    int s, d;
    if (e < E) { s = ei[e]; d = ei[E + e]; } else { s = d = e - E; }
    int pos = atomicAdd(&cursor[d], 1);
    csr[pos] = s;
}

// ---------- layer-1 fused softmax+aggregate (+bias+ELU): one wave per dst ----------
__global__ __launch_bounds__(256) void gat1_k(
    const int* __restrict__ csr, const int* __restrict__ rowptr,
    const float* __restrict__ as1, const float* __restrict__ ad1,
    const float* __restrict__ h1, const float* __restrict__ b1,
    float* __restrict__ out1, int N)
{
    int wid  = (blockIdx.x * 256 + threadIdx.x) >> 6;   // node = global wave id
    int lane = threadIdx.x & 63;
    if (wid >= N) return;
    const int start = rowptr[wid], end = rowptr[wid + 1];
    const float adA = ad1[wid * 4 + 0], adB = ad1[wid * 4 + 1];
    const float adC = ad1[wid * 4 + 2], adD = ad1[wid * 4 + 3];
    // pass 1: per-head max over incoming edges
    float m0 = -1e30f, m1 = -1e30f, m2 = -1e30f, m3 = -1e30f;
    for (int k = start + lane; k < end; k += 64) {
        int s = csr[k];
        m0 = fmaxf(m0, lrelu02(as1[s * 4 + 0] + adA));
        m1 = fmaxf(m1, lrelu02(as1[s * 4 + 1] + adB));
        m2 = fmaxf(m2, lrelu02(as1[s * 4 + 2] + adC));
        m3 = fmaxf(m3, lrelu02(as1[s * 4 + 3] + adD));
    }
    #pragma unroll
    for (int off = 32; off; off >>= 1) {
        m0 = fmaxf(m0, __shfl_xor(m0, off));
        m1 = fmaxf(m1, __shfl_xor(m1, off));
        m2 = fmaxf(m2, __shfl_xor(m2, off));
        m3 = fmaxf(m3, __shfl_xor(m3, off));
    }
    // pass 2: per-head denom
    float d0 = 0.f, d1 = 0.f, d2 = 0.f, d3 = 0.f;
    for (int k = start + lane; k < end; k += 64) {
        int s = csr[k];
        d0 += __expf(lrelu02(as1[s * 4 + 0] + adA) - m0);
        d1 += __expf(lrelu02(as1[s * 4 + 1] + adB) - m1);
        d2 += __expf(lrelu02(as1[s * 4 + 2] + adC) - m2);
        d3 += __expf(lrelu02(as1[s * 4 + 3] + adD) - m3);
    }
    #pragma unroll
    for (int off = 32; off; off >>= 1) {
        d0 += __shfl_xor(d0, off);
        d1 += __shfl_xor(d1, off);
        d2 += __shfl_xor(d2, off);
        d3 += __shfl_xor(d3, off);
    }
    // pass 3: aggregate — lane covers channels 2*lane, 2*lane+1; head = lane>>4
    const int hh = lane >> 4;
    const float mh  = hh == 0 ? m0 : hh == 1 ? m1 : hh == 2 ? m2 : m3;
    const float dh  = (hh == 0 ? d0 : hh == 1 ? d1 : hh == 2 ? d2 : d3) + 1e-16f;
    const float adh = hh == 0 ? adA : hh == 1 ? adB : hh == 2 ? adC : adD;
    const float rdh = 1.f / dh;
    float acc0 = 0.f, acc1 = 0.f;
    for (int k = start; k < end; ++k) {
        int s = csr[k];
        float v = lrelu02(as1[s * 4 + hh] + adh);
        float alpha = __expf(v - mh) * rdh;
        float2 hv = *(const float2*)(h1 + (size_t)s * 128 + lane * 2);
        acc0 = fmaf(hv.x, alpha, acc0);
        acc1 = fmaf(hv.y, alpha, acc1);
    }
    float v0 = acc0 + b1[lane * 2], v1 = acc1 + b1[lane * 2 + 1];
    v0 = v0 > 0.f ? v0 : expm1f(v0);
    v1 = v1 > 0.f ? v1 : expm1f(v1);
    *(float2*)(out1 + (size_t)wid * 128 + lane * 2) = make_float2(v0, v1);
}

// ---------- layer-2 dense: g = out1 @ W2 (+ attn dots), H=1 C=8 ----------
__global__ __launch_bounds__(256) void gemm2_k(
    const float* __restrict__ h2, const float* __restrict__ W2,
    const float* __restrict__ aw_s, const float* __restrict__ aw_d,
    float* __restrict__ g, float* __restrict__ as2, float* __restrict__ ad2, int N)
{
    __shared__ float W2l[128 * 8];
    __shared__ float rows[32][129];
    for (int i = threadIdx.x; i < 128 * 8; i += 256) W2l[i] = W2[i];
    const int r = threadIdx.x >> 3, j = threadIdx.x & 7;
    const float ws_ = aw_s[j], wd_ = aw_d[j];
    for (int base = blockIdx.x * 32; base < N; base += gridDim.x * 32) {
        __syncthreads();
        for (int i = threadIdx.x; i < 32 * 128; i += 256) {
            int rr = i >> 7, k = i & 127;
            int n = base + rr;
            rows[rr][k] = (n < N) ? h2[(size_t)n * 128 + k] : 0.f;
        }
        __syncthreads();
        int n = base + r;
        float acc = 0.f;
        #pragma unroll
        for (int k = 0; k < 128; ++k) acc += rows[r][k] * W2l[k * 8 + j];
        if (n < N) {
            g[n * 8 + j] = acc;
            float s = acc * ws_, d = acc * wd_;
            #pragma unroll
            for (int off = 4; off; off >>= 1) {
                s += __shfl_down(s, off, 8);
                d += __shfl_down(d, off, 8);
            }
            if (j == 0) { as2[n] = s; ad2[n] = d; }
        }
    }
}

// ---------- layer-2 fused softmax+aggregate+epilogue: 8 lanes per dst ----------
__global__ __launch_bounds__(256) void gat2_k(
    const int* __restrict__ csr, const int* __restrict__ rowptr,
    const float* __restrict__ as2, const float* __restrict__ ad2,
    const float* __restrict__ g, const float* __restrict__ b2_,
    const float* __restrict__ Wlin, const float* __restrict__ blin,
    float* __restrict__ out, int N)
{
    int idx = blockIdx.x * 256 + threadIdx.x;
    int n = idx >> 3, c = idx & 7;
    if (n >= N) return;
    const int start = rowptr[n], end = rowptr[n + 1];
    const float adh = ad2[n];
    float m = -1e30f;
    for (int k = start; k < end; ++k) m = fmaxf(m, lrelu02(as2[csr[k]] + adh));
    float den = 0.f;
    for (int k = start; k < end; ++k) den += __expf(lrelu02(as2[csr[k]] + adh) - m);
    const float rden = 1.f / (den + 1e-16f);
    float acc = 0.f;
    for (int k = start; k < end; ++k) {
        int s = csr[k];
        float alpha = __expf(lrelu02(as2[s] + adh) - m) * rden;
        acc = fmaf(g[s * 8 + c], alpha, acc);
    }
    float v = acc + b2_[c];
    v = v > 0.f ? v : expm1f(v);
    float t = v * Wlin[c];
    t += __shfl_xor(t, 1);
    t += __shfl_xor(t, 2);
    t += __shfl_xor(t, 4);
    if (c == 0) out[n] = 1.f / (1.f + __expf(-(t + blin[0])));
}

extern "C" void kernel_launch(void* const* d_in, const int* in_sizes, int n_in,
                              void* d_out, int out_size, void* d_ws, size_t ws_size,
                              hipStream_t stream)
{
    (void)n_in; (void)out_size; (void)ws_size;
    const float* x    = (const float*)d_in[0];
    const int*   ei   = (const int*)d_in[1];
    // d_in[2] = edge_attr, ignored
    const float* W1   = (const float*)d_in[3];
    const float* as1w = (const float*)d_in[4];
    const float* ad1w = (const float*)d_in[5];
    const float* b1   = (const float*)d_in[6];
    const float* W2   = (const float*)d_in[7];
    const float* as2w = (const float*)d_in[8];
    const float* ad2w = (const float*)d_in[9];
    const float* b2v  = (const float*)d_in[10];
    const float* Wlin = (const float*)d_in[11];
    const float* blin = (const float*)d_in[12];

    const int N = in_sizes[0] / 128;
    const int E = in_sizes[1] / 2;
    const int total = E + N;

    // workspace layout
    float* p = (float*)d_ws;
    float* h1   = p; p += (size_t)N * 128;   // 8B-aligned
    float* out1 = p; p += (size_t)N * 128;
    float* as1  = p; p += (size_t)N * 4;
    float* ad1  = p; p += (size_t)N * 4;
    float* g    = p; p += (size_t)N * 8;
    float* as2  = p; p += (size_t)N;
    float* ad2  = p; p += (size_t)N;
    int* deg    = (int*)p; p += (size_t)N;
    int* rowptr = (int*)p; p += (size_t)N + 1;
    int* cursor = (int*)p; p += (size_t)N;
    int* bsum   = (int*)p; p += ((size_t)N + 255) / 256;
    int* csr    = (int*)p; p += (size_t)total;

    const int eb = (total + 255) / 256;
    const int nb = (N + 255) / 256;

    // CSR build (overlaps nothing; graph static across layers)
    hipMemsetAsync(deg, 0, (size_t)N * sizeof(int), stream);
    gemm1_k<<<2048, 256, 0, stream>>>(x, W1, as1w, ad1w, h1, as1, ad1, N);
    degcnt_k<<<eb, 256, 0, stream>>>(ei, E, N, deg);
    blocksum_k<<<nb, 256, 0, stream>>>(deg, N, bsum);
    scanbsum_k<<<1, 1024, 0, stream>>>(bsum, nb);
    rowptr_k<<<nb, 256, 0, stream>>>(deg, bsum, N, E, rowptr, cursor);
    fill_k<<<eb, 256, 0, stream>>>(ei, E, N, cursor, csr);

    // layer 1: fused softmax + aggregate + bias + ELU
    gat1_k<<<(N * 64 + 255) / 256, 256, 0, stream>>>(csr, rowptr, as1, ad1, h1, b1, out1, N);

    // layer 2
    gemm2_k<<<3125, 256, 0, stream>>>(out1, W2, as2w, ad2w, g, as2, ad2, N);
    gat2_k<<<(N * 8 + 255) / 256, 256, 0, stream>>>(csr, rowptr, as2, ad2, g, b2v, Wlin, blin,
                                                    (float*)d_out, N);
}

// Round 4
// 704.772 us; speedup vs baseline: 2.7704x; 1.1814x over previous
//
#include <hip/hip_runtime.h>
#include <hip/hip_bf16.h>

__device__ __forceinline__ float lrelu02(float v) { return v > 0.f ? v : 0.2f * v; }

// ---------- layer-1 dense: h1 = x @ W1 (+ fused attn dots), register-tiled ----------
// Block = 256 threads -> 64 rows x 128 cols tile. Thread = 4 rows x 8 cols.
// W1 (64 KB) in LDS, read as 2x ds_read_b128/k (conflict-free, bcast across rowgroups).
// x read from global as float4 (block-exclusive rows -> read exactly once).
__global__ __launch_bounds__(256) void gemm1_k(
    const float* __restrict__ x, const float* __restrict__ W1,
    const float* __restrict__ aw_s, const float* __restrict__ aw_d,
    float* __restrict__ h1, float* __restrict__ as1, float* __restrict__ ad1, int N)
{
    __shared__ float Wl[128 * 128];   // 64 KB
    for (int i = threadIdx.x; i < 128 * 128 / 4; i += 256)
        ((float4*)Wl)[i] = ((const float4*)W1)[i];

    const int cl = threadIdx.x & 15;   // col-lane: cols cl*8 .. cl*8+7
    const int rg = threadIdx.x >> 4;   // row-group: rows row0 .. row0+3
    const int head = cl >> 2;          // all 8 cols lie in one head (32-col aligned)
    const int row0 = blockIdx.x * 64 + rg * 4;
    __syncthreads();

    const float4* x4[4];
    bool rv[4];
    #pragma unroll
    for (int r = 0; r < 4; ++r) {
        int rr = row0 + r;
        rv[r] = rr < N;
        int rc = rv[r] ? rr : (N - 1);                 // clamp: keep loads in-bounds
        x4[r] = (const float4*)(x + (size_t)rc * 128);
    }

    float acc[4][8];
    #pragma unroll
    for (int r = 0; r < 4; ++r)
        #pragma unroll
        for (int c = 0; c < 8; ++c) acc[r][c] = 0.f;

    for (int k4 = 0; k4 < 32; ++k4) {
        float4 xv[4];
        #pragma unroll
        for (int r = 0; r < 4; ++r) xv[r] = x4[r][k4];
        #pragma unroll
        for (int kk = 0; kk < 4; ++kk) {
            const int k = k4 * 4 + kk;
            const float4 w0 = *(const float4*)(Wl + k * 128 + cl * 8);
            const float4 w1 = *(const float4*)(Wl + k * 128 + cl * 8 + 4);
            #pragma unroll
            for (int r = 0; r < 4; ++r) {
                const float xk = kk == 0 ? xv[r].x : kk == 1 ? xv[r].y : kk == 2 ? xv[r].z : xv[r].w;
                acc[r][0] = fmaf(xk, w0.x, acc[r][0]);
                acc[r][1] = fmaf(xk, w0.y, acc[r][1]);
                acc[r][2] = fmaf(xk, w0.z, acc[r][2]);
                acc[r][3] = fmaf(xk, w0.w, acc[r][3]);
                acc[r][4] = fmaf(xk, w1.x, acc[r][4]);
                acc[r][5] = fmaf(xk, w1.y, acc[r][5]);
                acc[r][6] = fmaf(xk, w1.z, acc[r][6]);
                acc[r][7] = fmaf(xk, w1.w, acc[r][7]);
            }
        }
    }

    // attn-dot weights for this thread's 8 cols
    float ws_[8], wd_[8];
    #pragma unroll
    for (int c = 0; c < 8; ++c) { ws_[c] = aw_s[cl * 8 + c]; wd_[c] = aw_d[cl * 8 + c]; }

    #pragma unroll
    for (int r = 0; r < 4; ++r) {
        float s = 0.f, d = 0.f;
        #pragma unroll
        for (int c = 0; c < 8; ++c) { s = fmaf(acc[r][c], ws_[c], s); d = fmaf(acc[r][c], wd_[c], d); }
        // reduce across the 4 col-lanes sharing this head (cl bits 0,1; stays in rowgroup)
        s += __shfl_xor(s, 1); s += __shfl_xor(s, 2);
        d += __shfl_xor(d, 1); d += __shfl_xor(d, 2);
        if (rv[r]) {
            if ((cl & 3) == 0) { as1[(row0 + r) * 4 + head] = s; ad1[(row0 + r) * 4 + head] = d; }
            float* hp = h1 + (size_t)(row0 + r) * 128 + cl * 8;
            *(float4*)(hp)     = make_float4(acc[r][0], acc[r][1], acc[r][2], acc[r][3]);
            *(float4*)(hp + 4) = make_float4(acc[r][4], acc[r][5], acc[r][6], acc[r][7]);
        }
    }
}

// ---------- CSR build ----------
__global__ __launch_bounds__(256) void degcnt_k(
    const int* __restrict__ ei, int E, int N, int* __restrict__ deg)
{
    int e = blockIdx.x * 256 + threadIdx.x;
    if (e >= E + N) return;
    int d = (e < E) ? ei[E + e] : (e - E);
    atomicAdd(&deg[d], 1);
}

__global__ __launch_bounds__(256) void blocksum_k(
    const int* __restrict__ deg, int N, int* __restrict__ bsum)
{
    __shared__ int sh[256];
    int i = blockIdx.x * 256 + threadIdx.x;
    sh[threadIdx.x] = (i < N) ? deg[i] : 0;
    __syncthreads();
    for (int off = 128; off; off >>= 1) {
        if (threadIdx.x < off) sh[threadIdx.x] += sh[threadIdx.x + off];
        __syncthreads();
    }
    if (threadIdx.x == 0) bsum[blockIdx.x] = sh[0];
}

__global__ __launch_bounds__(1024) void scanbsum_k(int* __restrict__ bsum, int nb)
{
    __shared__ int buf[1024];
    __shared__ int carry;
    if (threadIdx.x == 0) carry = 0;
    __syncthreads();
    for (int base = 0; base < nb; base += 1024) {
        int i = base + threadIdx.x;
        int v = (i < nb) ? bsum[i] : 0;
        buf[threadIdx.x] = v;
        __syncthreads();
        for (int off = 1; off < 1024; off <<= 1) {
            int t = (threadIdx.x >= off) ? buf[threadIdx.x - off] : 0;
            __syncthreads();
            buf[threadIdx.x] += t;
            __syncthreads();
        }
        if (i < nb) bsum[i] = buf[threadIdx.x] - v + carry;   // exclusive
        __syncthreads();
        if (threadIdx.x == 0) carry += buf[1023];
        __syncthreads();
    }
}

__global__ __launch_bounds__(256) void rowptr_k(
    const int* __restrict__ deg, const int* __restrict__ bsum, int N, int E,
    int* __restrict__ rowptr, int* __restrict__ cursor)
{
    __shared__ int buf[256];
    int i = blockIdx.x * 256 + threadIdx.x;
    int v = (i < N) ? deg[i] : 0;
    buf[threadIdx.x] = v;
    __syncthreads();
    for (int off = 1; off < 256; off <<= 1) {
        int t = (threadIdx.x >= off) ? buf[threadIdx.x - off] : 0;
        __syncthreads();
        buf[threadIdx.x] += t;
        __syncthreads();
    }
    if (i < N) {
        int excl = bsum[blockIdx.x] + buf[threadIdx.x] - v;
        rowptr[i] = excl;
        cursor[i] = excl;
    }
    if (i == 0) rowptr[N] = E + N;
}

__global__ __launch_bounds__(256) void fill_k(
    const int* __restrict__ ei, int E, int N,
    int* __restrict__ cursor, int* __restrict__ csr)
{
    int e = blockIdx.x * 256 + threadIdx.x;
    if (e >= E + N) return;
    int s, d;
    if (e < E) { s = ei[e]; d = ei[E + e]; } else { s = d = e - E; }
    int pos = atomicAdd(&cursor[d], 1);
    csr[pos] = s;
}

// ---------- layer-1 fused softmax+aggregate (+bias+ELU): one wave per dst ----------
__global__ __launch_bounds__(256) void gat1_k(
    const int* __restrict__ csr, const int* __restrict__ rowptr,
    const float* __restrict__ as1, const float* __restrict__ ad1,
    const float* __restrict__ h1, const float* __restrict__ b1,
    float* __restrict__ out1, int N)
{
    int wid  = (blockIdx.x * 256 + threadIdx.x) >> 6;
    int lane = threadIdx.x & 63;
    if (wid >= N) return;
    const int start = rowptr[wid], end = rowptr[wid + 1];
    const float adA = ad1[wid * 4 + 0], adB = ad1[wid * 4 + 1];
    const float adC = ad1[wid * 4 + 2], adD = ad1[wid * 4 + 3];
    float m0 = -1e30f, m1 = -1e30f, m2 = -1e30f, m3 = -1e30f;
    for (int k = start + lane; k < end; k += 64) {
        int s = csr[k];
        m0 = fmaxf(m0, lrelu02(as1[s * 4 + 0] + adA));
        m1 = fmaxf(m1, lrelu02(as1[s * 4 + 1] + adB));
        m2 = fmaxf(m2, lrelu02(as1[s * 4 + 2] + adC));
        m3 = fmaxf(m3, lrelu02(as1[s * 4 + 3] + adD));
    }
    #pragma unroll
    for (int off = 32; off; off >>= 1) {
        m0 = fmaxf(m0, __shfl_xor(m0, off));
        m1 = fmaxf(m1, __shfl_xor(m1, off));
        m2 = fmaxf(m2, __shfl_xor(m2, off));
        m3 = fmaxf(m3, __shfl_xor(m3, off));
    }
    float d0 = 0.f, d1 = 0.f, d2 = 0.f, d3 = 0.f;
    for (int k = start + lane; k < end; k += 64) {
        int s = csr[k];
        d0 += __expf(lrelu02(as1[s * 4 + 0] + adA) - m0);
        d1 += __expf(lrelu02(as1[s * 4 + 1] + adB) - m1);
        d2 += __expf(lrelu02(as1[s * 4 + 2] + adC) - m2);
        d3 += __expf(lrelu02(as1[s * 4 + 3] + adD) - m3);
    }
    #pragma unroll
    for (int off = 32; off; off >>= 1) {
        d0 += __shfl_xor(d0, off);
        d1 += __shfl_xor(d1, off);
        d2 += __shfl_xor(d2, off);
        d3 += __shfl_xor(d3, off);
    }
    const int hh = lane >> 4;
    const float mh  = hh == 0 ? m0 : hh == 1 ? m1 : hh == 2 ? m2 : m3;
    const float dh  = (hh == 0 ? d0 : hh == 1 ? d1 : hh == 2 ? d2 : d3) + 1e-16f;
    const float adh = hh == 0 ? adA : hh == 1 ? adB : hh == 2 ? adC : adD;
    const float rdh = 1.f / dh;
    float acc0 = 0.f, acc1 = 0.f;
    for (int k = start; k < end; ++k) {
        int s = csr[k];
        float v = lrelu02(as1[s * 4 + hh] + adh);
        float alpha = __expf(v - mh) * rdh;
        float2 hv = *(const float2*)(h1 + (size_t)s * 128 + lane * 2);
        acc0 = fmaf(hv.x, alpha, acc0);
        acc1 = fmaf(hv.y, alpha, acc1);
    }
    float v0 = acc0 + b1[lane * 2], v1 = acc1 + b1[lane * 2 + 1];
    v0 = v0 > 0.f ? v0 : expm1f(v0);
    v1 = v1 > 0.f ? v1 : expm1f(v1);
    *(float2*)(out1 + (size_t)wid * 128 + lane * 2) = make_float2(v0, v1);
}

// ---------- layer-2 dense: g = out1 @ W2 (+ attn dots), H=1 C=8 ----------
__global__ __launch_bounds__(256) void gemm2_k(
    const float* __restrict__ h2, const float* __restrict__ W2,
    const float* __restrict__ aw_s, const float* __restrict__ aw_d,
    float* __restrict__ g, float* __restrict__ as2, float* __restrict__ ad2, int N)
{
    __shared__ float W2l[128 * 8];
    __shared__ float rows[32][129];
    for (int i = threadIdx.x; i < 128 * 8; i += 256) W2l[i] = W2[i];
    const int r = threadIdx.x >> 3, j = threadIdx.x & 7;
    const float ws_ = aw_s[j], wd_ = aw_d[j];
    for (int base = blockIdx.x * 32; base < N; base += gridDim.x * 32) {
        __syncthreads();
        for (int i = threadIdx.x; i < 32 * 128; i += 256) {
            int rr = i >> 7, k = i & 127;
            int n = base + rr;
            rows[rr][k] = (n < N) ? h2[(size_t)n * 128 + k] : 0.f;
        }
        __syncthreads();
        int n = base + r;
        float acc = 0.f;
        #pragma unroll
        for (int k = 0; k < 128; ++k) acc += rows[r][k] * W2l[k * 8 + j];
        if (n < N) {
            g[n * 8 + j] = acc;
            float s = acc * ws_, d = acc * wd_;
            #pragma unroll
            for (int off = 4; off; off >>= 1) {
                s += __shfl_down(s, off, 8);
                d += __shfl_down(d, off, 8);
            }
            if (j == 0) { as2[n] = s; ad2[n] = d; }
        }
    }
}

// ---------- layer-2 fused softmax+aggregate+epilogue: 8 lanes per dst ----------
__global__ __launch_bounds__(256) void gat2_k(
    const int* __restrict__ csr, const int* __restrict__ rowptr,
    const float* __restrict__ as2, const float* __restrict__ ad2,
    const float* __restrict__ g, const float* __restrict__ b2_,
    const float* __restrict__ Wlin, const float* __restrict__ blin,
    float* __restrict__ out, int N)
{
    int idx = blockIdx.x * 256 + threadIdx.x;
    int n = idx >> 3, c = idx & 7;
    if (n >= N) return;
    const int start = rowptr[n], end = rowptr[n + 1];
    const float adh = ad2[n];
    float m = -1e30f;
    for (int k = start; k < end; ++k) m = fmaxf(m, lrelu02(as2[csr[k]] + adh));
    float den = 0.f;
    for (int k = start; k < end; ++k) den += __expf(lrelu02(as2[csr[k]] + adh) - m);
    const float rden = 1.f / (den + 1e-16f);
    float acc = 0.f;
    for (int k = start; k < end; ++k) {
        int s = csr[k];
        float alpha = __expf(lrelu02(as2[s] + adh) - m) * rden;
        acc = fmaf(g[s * 8 + c], alpha, acc);
    }
    float v = acc + b2_[c];
    v = v > 0.f ? v : expm1f(v);
    float t = v * Wlin[c];
    t += __shfl_xor(t, 1);
    t += __shfl_xor(t, 2);
    t += __shfl_xor(t, 4);
    if (c == 0) out[n] = 1.f / (1.f + __expf(-(t + blin[0])));
}

extern "C" void kernel_launch(void* const* d_in, const int* in_sizes, int n_in,
                              void* d_out, int out_size, void* d_ws, size_t ws_size,
                              hipStream_t stream)
{
    (void)n_in; (void)out_size; (void)ws_size;
    const float* x    = (const float*)d_in[0];
    const int*   ei   = (const int*)d_in[1];
    // d_in[2] = edge_attr, ignored
    const float* W1   = (const float*)d_in[3];
    const float* as1w = (const float*)d_in[4];
    const float* ad1w = (const float*)d_in[5];
    const float* b1   = (const float*)d_in[6];
    const float* W2   = (const float*)d_in[7];
    const float* as2w = (const float*)d_in[8];
    const float* ad2w = (const float*)d_in[9];
    const float* b2v  = (const float*)d_in[10];
    const float* Wlin = (const float*)d_in[11];
    const float* blin = (const float*)d_in[12];

    const int N = in_sizes[0] / 128;
    const int E = in_sizes[1] / 2;
    const int total = E + N;

    // workspace layout
    float* p = (float*)d_ws;
    float* h1   = p; p += (size_t)N * 128;
    float* out1 = p; p += (size_t)N * 128;
    float* as1  = p; p += (size_t)N * 4;
    float* ad1  = p; p += (size_t)N * 4;
    float* g    = p; p += (size_t)N * 8;
    float* as2  = p; p += (size_t)N;
    float* ad2  = p; p += (size_t)N;
    int* deg    = (int*)p; p += (size_t)N;
    int* rowptr = (int*)p; p += (size_t)N + 1;
    int* cursor = (int*)p; p += (size_t)N;
    int* bsum   = (int*)p; p += ((size_t)N + 255) / 256;
    int* csr    = (int*)p; p += (size_t)total;

    const int eb = (total + 255) / 256;
    const int nb = (N + 255) / 256;

    hipMemsetAsync(deg, 0, (size_t)N * sizeof(int), stream);
    gemm1_k<<<(N + 63) / 64, 256, 0, stream>>>(x, W1, as1w, ad1w, h1, as1, ad1, N);
    degcnt_k<<<eb, 256, 0, stream>>>(ei, E, N, deg);
    blocksum_k<<<nb, 256, 0, stream>>>(deg, N, bsum);
    scanbsum_k<<<1, 1024, 0, stream>>>(bsum, nb);
    rowptr_k<<<nb, 256, 0, stream>>>(deg, bsum, N, E, rowptr, cursor);
    fill_k<<<eb, 256, 0, stream>>>(ei, E, N, cursor, csr);

    // layer 1: fused softmax + aggregate + bias + ELU
    gat1_k<<<(N * 64 + 255) / 256, 256, 0, stream>>>(csr, rowptr, as1, ad1, h1, b1, out1, N);

    // layer 2
    gemm2_k<<<3125, 256, 0, stream>>>(out1, W2, as2w, ad2w, g, as2, ad2, N);
    gat2_k<<<(N * 8 + 255) / 256, 256, 0, stream>>>(csr, rowptr, as2, ad2, g, b2v, Wlin, blin,
                                                    (float*)d_out, N);
}

// Round 5
// 679.831 us; speedup vs baseline: 2.8721x; 1.0367x over previous
//
#include <hip/hip_runtime.h>
#include <hip/hip_bf16.h>

__device__ __forceinline__ float lrelu02(float v) { return v > 0.f ? v : 0.2f * v; }

// manual bf16 <-> f32 (RNE); avoids API differences, finite data only
__device__ __forceinline__ float bf2f(unsigned short u) {
    union { unsigned int i; float f; } v; v.i = ((unsigned int)u) << 16; return v.f;
}
__device__ __forceinline__ unsigned short f2bf(float f) {
    union { float f; unsigned int i; } v; v.f = f;
    unsigned int x = v.i;
    return (unsigned short)((x + 0x7fffu + ((x >> 16) & 1u)) >> 16);
}

// ---------- layer-1 dense: h1 = x @ W1 (+ fused attn dots), register-tiled ----------
// Block = 256 threads -> 64 rows x 128 cols tile. Thread = 4 rows x 8 cols.
// h1 stored bf16 (halves the gat1 gather traffic); attn dots from fp32 accs.
__global__ __launch_bounds__(256) void gemm1_k(
    const float* __restrict__ x, const float* __restrict__ W1,
    const float* __restrict__ aw_s, const float* __restrict__ aw_d,
    unsigned short* __restrict__ h1b, float* __restrict__ as1, float* __restrict__ ad1, int N)
{
    __shared__ float Wl[128 * 128];   // 64 KB
    for (int i = threadIdx.x; i < 128 * 128 / 4; i += 256)
        ((float4*)Wl)[i] = ((const float4*)W1)[i];

    const int cl = threadIdx.x & 15;   // col-lane: cols cl*8 .. cl*8+7
    const int rg = threadIdx.x >> 4;   // row-group: rows row0 .. row0+3
    const int head = cl >> 2;          // all 8 cols lie in one head
    const int row0 = blockIdx.x * 64 + rg * 4;
    __syncthreads();

    const float4* x4[4];
    bool rv[4];
    #pragma unroll
    for (int r = 0; r < 4; ++r) {
        int rr = row0 + r;
        rv[r] = rr < N;
        int rc = rv[r] ? rr : (N - 1);
        x4[r] = (const float4*)(x + (size_t)rc * 128);
    }

    float acc[4][8];
    #pragma unroll
    for (int r = 0; r < 4; ++r)
        #pragma unroll
        for (int c = 0; c < 8; ++c) acc[r][c] = 0.f;

    for (int k4 = 0; k4 < 32; ++k4) {
        float4 xv[4];
        #pragma unroll
        for (int r = 0; r < 4; ++r) xv[r] = x4[r][k4];
        #pragma unroll
        for (int kk = 0; kk < 4; ++kk) {
            const int k = k4 * 4 + kk;
            const float4 w0 = *(const float4*)(Wl + k * 128 + cl * 8);
            const float4 w1 = *(const float4*)(Wl + k * 128 + cl * 8 + 4);
            #pragma unroll
            for (int r = 0; r < 4; ++r) {
                const float xk = kk == 0 ? xv[r].x : kk == 1 ? xv[r].y : kk == 2 ? xv[r].z : xv[r].w;
                acc[r][0] = fmaf(xk, w0.x, acc[r][0]);
                acc[r][1] = fmaf(xk, w0.y, acc[r][1]);
                acc[r][2] = fmaf(xk, w0.z, acc[r][2]);
                acc[r][3] = fmaf(xk, w0.w, acc[r][3]);
                acc[r][4] = fmaf(xk, w1.x, acc[r][4]);
                acc[r][5] = fmaf(xk, w1.y, acc[r][5]);
                acc[r][6] = fmaf(xk, w1.z, acc[r][6]);
                acc[r][7] = fmaf(xk, w1.w, acc[r][7]);
            }
        }
    }

    float ws_[8], wd_[8];
    #pragma unroll
    for (int c = 0; c < 8; ++c) { ws_[c] = aw_s[cl * 8 + c]; wd_[c] = aw_d[cl * 8 + c]; }

    #pragma unroll
    for (int r = 0; r < 4; ++r) {
        float s = 0.f, d = 0.f;
        #pragma unroll
        for (int c = 0; c < 8; ++c) { s = fmaf(acc[r][c], ws_[c], s); d = fmaf(acc[r][c], wd_[c], d); }
        s += __shfl_xor(s, 1); s += __shfl_xor(s, 2);
        d += __shfl_xor(d, 1); d += __shfl_xor(d, 2);
        if (rv[r]) {
            if ((cl & 3) == 0) { as1[(row0 + r) * 4 + head] = s; ad1[(row0 + r) * 4 + head] = d; }
            uint4 pk;
            pk.x = f2bf(acc[r][0]) | ((unsigned)f2bf(acc[r][1]) << 16);
            pk.y = f2bf(acc[r][2]) | ((unsigned)f2bf(acc[r][3]) << 16);
            pk.z = f2bf(acc[r][4]) | ((unsigned)f2bf(acc[r][5]) << 16);
            pk.w = f2bf(acc[r][6]) | ((unsigned)f2bf(acc[r][7]) << 16);
            *(uint4*)(h1b + (size_t)(row0 + r) * 128 + cl * 8) = pk;
        }
    }
}

// ---------- CSR build ----------
__global__ __launch_bounds__(256) void degcnt_k(
    const int* __restrict__ ei, int E, int N, int* __restrict__ deg)
{
    int e = blockIdx.x * 256 + threadIdx.x;
    if (e >= E + N) return;
    int d = (e < E) ? ei[E + e] : (e - E);
    atomicAdd(&deg[d], 1);
}

__global__ __launch_bounds__(256) void blocksum_k(
    const int* __restrict__ deg, int N, int* __restrict__ bsum)
{
    __shared__ int sh[256];
    int i = blockIdx.x * 256 + threadIdx.x;
    sh[threadIdx.x] = (i < N) ? deg[i] : 0;
    __syncthreads();
    for (int off = 128; off; off >>= 1) {
        if (threadIdx.x < off) sh[threadIdx.x] += sh[threadIdx.x + off];
        __syncthreads();
    }
    if (threadIdx.x == 0) bsum[blockIdx.x] = sh[0];
}

__global__ __launch_bounds__(1024) void scanbsum_k(int* __restrict__ bsum, int nb)
{
    __shared__ int buf[1024];
    __shared__ int carry;
    if (threadIdx.x == 0) carry = 0;
    __syncthreads();
    for (int base = 0; base < nb; base += 1024) {
        int i = base + threadIdx.x;
        int v = (i < nb) ? bsum[i] : 0;
        buf[threadIdx.x] = v;
        __syncthreads();
        for (int off = 1; off < 1024; off <<= 1) {
            int t = (threadIdx.x >= off) ? buf[threadIdx.x - off] : 0;
            __syncthreads();
            buf[threadIdx.x] += t;
            __syncthreads();
        }
        if (i < nb) bsum[i] = buf[threadIdx.x] - v + carry;   // exclusive
        __syncthreads();
        if (threadIdx.x == 0) carry += buf[1023];
        __syncthreads();
    }
}

__global__ __launch_bounds__(256) void rowptr_k(
    const int* __restrict__ deg, const int* __restrict__ bsum, int N, int E,
    int* __restrict__ rowptr, int* __restrict__ cursor)
{
    __shared__ int buf[256];
    int i = blockIdx.x * 256 + threadIdx.x;
    int v = (i < N) ? deg[i] : 0;
    buf[threadIdx.x] = v;
    __syncthreads();
    for (int off = 1; off < 256; off <<= 1) {
        int t = (threadIdx.x >= off) ? buf[threadIdx.x - off] : 0;
        __syncthreads();
        buf[threadIdx.x] += t;
        __syncthreads();
    }
    if (i < N) {
        int excl = bsum[blockIdx.x] + buf[threadIdx.x] - v;
        rowptr[i] = excl;
        cursor[i] = excl;
    }
    if (i == 0) rowptr[N] = E + N;
}

__global__ __launch_bounds__(256) void fill_k(
    const int* __restrict__ ei, int E, int N,
    int* __restrict__ cursor, int* __restrict__ csr)
{
    int e = blockIdx.x * 256 + threadIdx.x;
    if (e >= E + N) return;
    int s, d;
    if (e < E) { s = ei[e]; d = ei[E + e]; } else { s = d = e - E; }
    int pos = atomicAdd(&cursor[d], 1);
    csr[pos] = s;
}

// ---------- layer-1 fused softmax+aggregate (+bias+ELU): one wave per dst ----------
__global__ __launch_bounds__(256) void gat1_k(
    const int* __restrict__ csr, const int* __restrict__ rowptr,
    const float* __restrict__ as1, const float* __restrict__ ad1,
    const unsigned short* __restrict__ h1b, const float* __restrict__ b1,
    unsigned short* __restrict__ out1b, int N)
{
    int wid  = (blockIdx.x * 256 + threadIdx.x) >> 6;
    int lane = threadIdx.x & 63;
    if (wid >= N) return;
    const int start = rowptr[wid], end = rowptr[wid + 1];
    const float adA = ad1[wid * 4 + 0], adB = ad1[wid * 4 + 1];
    const float adC = ad1[wid * 4 + 2], adD = ad1[wid * 4 + 3];
    float m0 = -1e30f, m1 = -1e30f, m2 = -1e30f, m3 = -1e30f;
    for (int k = start + lane; k < end; k += 64) {
        int s = csr[k];
        m0 = fmaxf(m0, lrelu02(as1[s * 4 + 0] + adA));
        m1 = fmaxf(m1, lrelu02(as1[s * 4 + 1] + adB));
        m2 = fmaxf(m2, lrelu02(as1[s * 4 + 2] + adC));
        m3 = fmaxf(m3, lrelu02(as1[s * 4 + 3] + adD));
    }
    #pragma unroll
    for (int off = 32; off; off >>= 1) {
        m0 = fmaxf(m0, __shfl_xor(m0, off));
        m1 = fmaxf(m1, __shfl_xor(m1, off));
        m2 = fmaxf(m2, __shfl_xor(m2, off));
        m3 = fmaxf(m3, __shfl_xor(m3, off));
    }
    float d0 = 0.f, d1 = 0.f, d2 = 0.f, d3 = 0.f;
    for (int k = start + lane; k < end; k += 64) {
        int s = csr[k];
        d0 += __expf(lrelu02(as1[s * 4 + 0] + adA) - m0);
        d1 += __expf(lrelu02(as1[s * 4 + 1] + adB) - m1);
        d2 += __expf(lrelu02(as1[s * 4 + 2] + adC) - m2);
        d3 += __expf(lrelu02(as1[s * 4 + 3] + adD) - m3);
    }
    #pragma unroll
    for (int off = 32; off; off >>= 1) {
        d0 += __shfl_xor(d0, off);
        d1 += __shfl_xor(d1, off);
        d2 += __shfl_xor(d2, off);
        d3 += __shfl_xor(d3, off);
    }
    const int hh = lane >> 4;
    const float mh  = hh == 0 ? m0 : hh == 1 ? m1 : hh == 2 ? m2 : m3;
    const float dh  = (hh == 0 ? d0 : hh == 1 ? d1 : hh == 2 ? d2 : d3) + 1e-16f;
    const float adh = hh == 0 ? adA : hh == 1 ? adB : hh == 2 ? adC : adD;
    const float rdh = 1.f / dh;
    float acc0 = 0.f, acc1 = 0.f;
    for (int k = start; k < end; ++k) {
        int s = csr[k];
        float v = lrelu02(as1[s * 4 + hh] + adh);
        float alpha = __expf(v - mh) * rdh;
        unsigned int pv = *(const unsigned int*)(h1b + (size_t)s * 128 + lane * 2);
        acc0 = fmaf(bf2f((unsigned short)pv), alpha, acc0);
        acc1 = fmaf(bf2f((unsigned short)(pv >> 16)), alpha, acc1);
    }
    float v0 = acc0 + b1[lane * 2], v1 = acc1 + b1[lane * 2 + 1];
    v0 = v0 > 0.f ? v0 : expm1f(v0);
    v1 = v1 > 0.f ? v1 : expm1f(v1);
    *(unsigned int*)(out1b + (size_t)wid * 128 + lane * 2) =
        f2bf(v0) | ((unsigned)f2bf(v1) << 16);
}

// ---------- layer-2 dense: g = out1 @ W2 (+ attn dots), H=1 C=8, bf16 input ----------
__global__ __launch_bounds__(256) void gemm2_k(
    const unsigned short* __restrict__ h2b, const float* __restrict__ W2,
    const float* __restrict__ aw_s, const float* __restrict__ aw_d,
    float* __restrict__ g, float* __restrict__ as2, float* __restrict__ ad2, int N)
{
    __shared__ float W2l[128 * 8];
    __shared__ float rows[32][129];
    for (int i = threadIdx.x; i < 128 * 8; i += 256) W2l[i] = W2[i];
    const int r = threadIdx.x >> 3, j = threadIdx.x & 7;
    const float ws_ = aw_s[j], wd_ = aw_d[j];
    for (int base = blockIdx.x * 32; base < N; base += gridDim.x * 32) {
        __syncthreads();
        for (int i = threadIdx.x; i < 32 * 64; i += 256) {
            int rr = i >> 6, kp = i & 63;
            int n = base + rr;
            unsigned int pv = (n < N) ? *(const unsigned int*)(h2b + (size_t)n * 128 + kp * 2) : 0u;
            rows[rr][kp * 2]     = bf2f((unsigned short)pv);
            rows[rr][kp * 2 + 1] = bf2f((unsigned short)(pv >> 16));
        }
        __syncthreads();
        int n = base + r;
        float acc = 0.f;
        #pragma unroll
        for (int k = 0; k < 128; ++k) acc += rows[r][k] * W2l[k * 8 + j];
        if (n < N) {
            g[n * 8 + j] = acc;
            float s = acc * ws_, d = acc * wd_;
            #pragma unroll
            for (int off = 4; off; off >>= 1) {
                s += __shfl_down(s, off, 8);
                d += __shfl_down(d, off, 8);
            }
            if (j == 0) { as2[n] = s; ad2[n] = d; }
        }
    }
}

// ---------- layer-2 fused softmax+aggregate+epilogue: 8 lanes per dst ----------
__global__ __launch_bounds__(256) void gat2_k(
    const int* __restrict__ csr, const int* __restrict__ rowptr,
    const float* __restrict__ as2, const float* __restrict__ ad2,
    const float* __restrict__ g, const float* __restrict__ b2_,
    const float* __restrict__ Wlin, const float* __restrict__ blin,
    float* __restrict__ out, int N)
{
    int idx = blockIdx.x * 256 + threadIdx.x;
    int n = idx >> 3, c = idx & 7;
    if (n >= N) return;
    const int start = rowptr[n], end = rowptr[n + 1];
    const float adh = ad2[n];
    float m = -1e30f;
    for (int k = start; k < end; ++k) m = fmaxf(m, lrelu02(as2[csr[k]] + adh));
    float den = 0.f;
    for (int k = start; k < end; ++k) den += __expf(lrelu02(as2[csr[k]] + adh) - m);
    const float rden = 1.f / (den + 1e-16f);
    float acc = 0.f;
    for (int k = start; k < end; ++k) {
        int s = csr[k];
        float alpha = __expf(lrelu02(as2[s] + adh) - m) * rden;
        acc = fmaf(g[s * 8 + c], alpha, acc);
    }
    float v = acc + b2_[c];
    v = v > 0.f ? v : expm1f(v);
    float t = v * Wlin[c];
    t += __shfl_xor(t, 1);
    t += __shfl_xor(t, 2);
    t += __shfl_xor(t, 4);
    if (c == 0) out[n] = 1.f / (1.f + __expf(-(t + blin[0])));
}

extern "C" void kernel_launch(void* const* d_in, const int* in_sizes, int n_in,
                              void* d_out, int out_size, void* d_ws, size_t ws_size,
                              hipStream_t stream)
{
    (void)n_in; (void)out_size; (void)ws_size;
    const float* x    = (const float*)d_in[0];
    const int*   ei   = (const int*)d_in[1];
    // d_in[2] = edge_attr, ignored
    const float* W1   = (const float*)d_in[3];
    const float* as1w = (const float*)d_in[4];
    const float* ad1w = (const float*)d_in[5];
    const float* b1   = (const float*)d_in[6];
    const float* W2   = (const float*)d_in[7];
    const float* as2w = (const float*)d_in[8];
    const float* ad2w = (const float*)d_in[9];
    const float* b2v  = (const float*)d_in[10];
    const float* Wlin = (const float*)d_in[11];
    const float* blin = (const float*)d_in[12];

    const int N = in_sizes[0] / 128;
    const int E = in_sizes[1] / 2;
    const int total = E + N;

    // workspace layout
    float* p = (float*)d_ws;
    unsigned short* h1b   = (unsigned short*)p; p += (size_t)N * 64;  // N*128 bf16
    unsigned short* out1b = (unsigned short*)p; p += (size_t)N * 64;
    float* as1  = p; p += (size_t)N * 4;
    float* ad1  = p; p += (size_t)N * 4;
    float* g    = p; p += (size_t)N * 8;
    float* as2  = p; p += (size_t)N;
    float* ad2  = p; p += (size_t)N;
    int* deg    = (int*)p; p += (size_t)N;
    int* rowptr = (int*)p; p += (size_t)N + 1;
    int* cursor = (int*)p; p += (size_t)N;
    int* bsum   = (int*)p; p += ((size_t)N + 255) / 256;
    int* csr    = (int*)p; p += (size_t)total;

    const int eb = (total + 255) / 256;
    const int nb = (N + 255) / 256;

    hipMemsetAsync(deg, 0, (size_t)N * sizeof(int), stream);
    gemm1_k<<<(N + 63) / 64, 256, 0, stream>>>(x, W1, as1w, ad1w, h1b, as1, ad1, N);
    degcnt_k<<<eb, 256, 0, stream>>>(ei, E, N, deg);
    blocksum_k<<<nb, 256, 0, stream>>>(deg, N, bsum);
    scanbsum_k<<<1, 1024, 0, stream>>>(bsum, nb);
    rowptr_k<<<nb, 256, 0, stream>>>(deg, bsum, N, E, rowptr, cursor);
    fill_k<<<eb, 256, 0, stream>>>(ei, E, N, cursor, csr);

    // layer 1: fused softmax + aggregate + bias + ELU
    gat1_k<<<(N * 64 + 255) / 256, 256, 0, stream>>>(csr, rowptr, as1, ad1, h1b, b1, out1b, N);

    // layer 2
    gemm2_k<<<3125, 256, 0, stream>>>(out1b, W2, as2w, ad2w, g, as2, ad2, N);
    gat2_k<<<(N * 8 + 255) / 256, 256, 0, stream>>>(csr, rowptr, as2, ad2, g, b2v, Wlin, blin,
                                                    (float*)d_out, N);
}

// Round 6
// 543.989 us; speedup vs baseline: 3.5893x; 1.2497x over previous
//
#include <hip/hip_runtime.h>
#include <hip/hip_bf16.h>

__device__ __forceinline__ float lrelu02(float v) { return v > 0.f ? v : 0.2f * v; }

// manual bf16 <-> f32 (RNE); finite data only
__device__ __forceinline__ float bf2f(unsigned short u) {
    union { unsigned int i; float f; } v; v.i = ((unsigned int)u) << 16; return v.f;
}
__device__ __forceinline__ unsigned short f2bf(float f) {
    union { float f; unsigned int i; } v; v.f = f;
    unsigned int x = v.i;
    return (unsigned short)((x + 0x7fffu + ((x >> 16) & 1u)) >> 16);
}

// ---------- layer-1 dense: h1 = x @ W1 (+ fused attn dots), register-tiled ----------
__global__ __launch_bounds__(256) void gemm1_k(
    const float* __restrict__ x, const float* __restrict__ W1,
    const float* __restrict__ aw_s, const float* __restrict__ aw_d,
    unsigned short* __restrict__ h1b, float* __restrict__ as1, float* __restrict__ ad1, int N)
{
    __shared__ float Wl[128 * 128];   // 64 KB
    for (int i = threadIdx.x; i < 128 * 128 / 4; i += 256)
        ((float4*)Wl)[i] = ((const float4*)W1)[i];

    const int cl = threadIdx.x & 15;
    const int rg = threadIdx.x >> 4;
    const int head = cl >> 2;
    const int row0 = blockIdx.x * 64 + rg * 4;
    __syncthreads();

    const float4* x4[4];
    bool rv[4];
    #pragma unroll
    for (int r = 0; r < 4; ++r) {
        int rr = row0 + r;
        rv[r] = rr < N;
        int rc = rv[r] ? rr : (N - 1);
        x4[r] = (const float4*)(x + (size_t)rc * 128);
    }

    float acc[4][8];
    #pragma unroll
    for (int r = 0; r < 4; ++r)
        #pragma unroll
        for (int c = 0; c < 8; ++c) acc[r][c] = 0.f;

    for (int k4 = 0; k4 < 32; ++k4) {
        float4 xv[4];
        #pragma unroll
        for (int r = 0; r < 4; ++r) xv[r] = x4[r][k4];
        #pragma unroll
        for (int kk = 0; kk < 4; ++kk) {
            const int k = k4 * 4 + kk;
            const float4 w0 = *(const float4*)(Wl + k * 128 + cl * 8);
            const float4 w1 = *(const float4*)(Wl + k * 128 + cl * 8 + 4);
            #pragma unroll
            for (int r = 0; r < 4; ++r) {
                const float xk = kk == 0 ? xv[r].x : kk == 1 ? xv[r].y : kk == 2 ? xv[r].z : xv[r].w;
                acc[r][0] = fmaf(xk, w0.x, acc[r][0]);
                acc[r][1] = fmaf(xk, w0.y, acc[r][1]);
                acc[r][2] = fmaf(xk, w0.z, acc[r][2]);
                acc[r][3] = fmaf(xk, w0.w, acc[r][3]);
                acc[r][4] = fmaf(xk, w1.x, acc[r][4]);
                acc[r][5] = fmaf(xk, w1.y, acc[r][5]);
                acc[r][6] = fmaf(xk, w1.z, acc[r][6]);
                acc[r][7] = fmaf(xk, w1.w, acc[r][7]);
            }
        }
    }

    float ws_[8], wd_[8];
    #pragma unroll
    for (int c = 0; c < 8; ++c) { ws_[c] = aw_s[cl * 8 + c]; wd_[c] = aw_d[cl * 8 + c]; }

    #pragma unroll
    for (int r = 0; r < 4; ++r) {
        float s = 0.f, d = 0.f;
        #pragma unroll
        for (int c = 0; c < 8; ++c) { s = fmaf(acc[r][c], ws_[c], s); d = fmaf(acc[r][c], wd_[c], d); }
        s += __shfl_xor(s, 1); s += __shfl_xor(s, 2);
        d += __shfl_xor(d, 1); d += __shfl_xor(d, 2);
        if (rv[r]) {
            if ((cl & 3) == 0) { as1[(row0 + r) * 4 + head] = s; ad1[(row0 + r) * 4 + head] = d; }
            uint4 pk;
            pk.x = f2bf(acc[r][0]) | ((unsigned)f2bf(acc[r][1]) << 16);
            pk.y = f2bf(acc[r][2]) | ((unsigned)f2bf(acc[r][3]) << 16);
            pk.z = f2bf(acc[r][4]) | ((unsigned)f2bf(acc[r][5]) << 16);
            pk.w = f2bf(acc[r][6]) | ((unsigned)f2bf(acc[r][7]) << 16);
            *(uint4*)(h1b + (size_t)(row0 + r) * 128 + cl * 8) = pk;
        }
    }
}

// ---------- CSR build ----------
__global__ __launch_bounds__(256) void degcnt_k(
    const int* __restrict__ ei, int E, int N, int* __restrict__ deg)
{
    int e = blockIdx.x * 256 + threadIdx.x;
    if (e >= E + N) return;
    int d = (e < E) ? ei[E + e] : (e - E);
    atomicAdd(&deg[d], 1);
}

__global__ __launch_bounds__(256) void blocksum_k(
    const int* __restrict__ deg, int N, int* __restrict__ bsum)
{
    __shared__ int sh[256];
    int i = blockIdx.x * 256 + threadIdx.x;
    sh[threadIdx.x] = (i < N) ? deg[i] : 0;
    __syncthreads();
    for (int off = 128; off; off >>= 1) {
        if (threadIdx.x < off) sh[threadIdx.x] += sh[threadIdx.x + off];
        __syncthreads();
    }
    if (threadIdx.x == 0) bsum[blockIdx.x] = sh[0];
}

__global__ __launch_bounds__(1024) void scanbsum_k(int* __restrict__ bsum, int nb)
{
    __shared__ int buf[1024];
    __shared__ int carry;
    if (threadIdx.x == 0) carry = 0;
    __syncthreads();
    for (int base = 0; base < nb; base += 1024) {
        int i = base + threadIdx.x;
        int v = (i < nb) ? bsum[i] : 0;
        buf[threadIdx.x] = v;
        __syncthreads();
        for (int off = 1; off < 1024; off <<= 1) {
            int t = (threadIdx.x >= off) ? buf[threadIdx.x - off] : 0;
            __syncthreads();
            buf[threadIdx.x] += t;
            __syncthreads();
        }
        if (i < nb) bsum[i] = buf[threadIdx.x] - v + carry;   // exclusive
        __syncthreads();
        if (threadIdx.x == 0) carry += buf[1023];
        __syncthreads();
    }
}

__global__ __launch_bounds__(256) void rowptr_k(
    const int* __restrict__ deg, const int* __restrict__ bsum, int N, int E,
    int* __restrict__ rowptr, int* __restrict__ cursor)
{
    __shared__ int buf[256];
    int i = blockIdx.x * 256 + threadIdx.x;
    int v = (i < N) ? deg[i] : 0;
    buf[threadIdx.x] = v;
    __syncthreads();
    for (int off = 1; off < 256; off <<= 1) {
        int t = (threadIdx.x >= off) ? buf[threadIdx.x - off] : 0;
        __syncthreads();
        buf[threadIdx.x] += t;
        __syncthreads();
    }
    if (i < N) {
        int excl = bsum[blockIdx.x] + buf[threadIdx.x] - v;
        rowptr[i] = excl;
        cursor[i] = excl;
    }
    if (i == 0) rowptr[N] = E + N;
}

__global__ __launch_bounds__(256) void fill_k(
    const int* __restrict__ ei, int E, int N,
    int* __restrict__ cursor, int* __restrict__ csr)
{
    int e = blockIdx.x * 256 + threadIdx.x;
    if (e >= E + N) return;
    int s, d;
    if (e < E) { s = ei[e]; d = ei[E + e]; } else { s = d = e - E; }
    int pos = atomicAdd(&cursor[d], 1);
    csr[pos] = s;
}

// ---------- layer-1 single-pass softmax-aggregate (+bias+ELU): one wave per dst ----------
// alpha = exp(v - m_self) / sum(exp(v - m_self)) -- linear, so accumulate num & den in one pass.
// Chunk of 16 edges: lanes compute 16 edges x 4 heads of w in parallel; inner accumulate
// broadcasts s via readlane (scalar load base) and w via shfl(width=16).
__global__ __launch_bounds__(256) void gat1_k(
    const int* __restrict__ csr, const int* __restrict__ rowptr,
    const float* __restrict__ as1, const float* __restrict__ ad1,
    const unsigned short* __restrict__ h1b, const float* __restrict__ b1,
    unsigned short* __restrict__ out1b, int N)
{
    const int wid  = (blockIdx.x * 256 + threadIdx.x) >> 6;
    const int lane = threadIdx.x & 63;
    if (wid >= N) return;
    const int start = rowptr[wid], end = rowptr[wid + 1];
    const int i16 = lane & 15;        // edge slot within chunk
    const int hh  = lane >> 4;        // head for w-compute AND for my channels (c/32 == lane/16)
    const float adh = ad1[wid * 4 + hh];
    const float mh  = lrelu02(as1[wid * 4 + hh] + adh);   // self-logit offset (den >= 1)
    const unsigned short* hb = h1b + lane * 2;

    float den = 0.f, acc0 = 0.f, acc1 = 0.f;
    int k0 = start;
    for (; k0 + 16 <= end; k0 += 16) {
        int s = csr[k0 + i16];
        float w = __expf(lrelu02(as1[s * 4 + hh] + adh) - mh);
        den += w;
        #pragma unroll
        for (int e = 0; e < 16; ++e) {
            int se = __builtin_amdgcn_readlane(s, e);          // uniform -> scalar base
            float we = __shfl(w, e, 16);                       // per-head broadcast
            unsigned int pv = *(const unsigned int*)(hb + (size_t)se * 128);
            acc0 = fmaf(bf2f((unsigned short)pv), we, acc0);
            acc1 = fmaf(bf2f((unsigned short)(pv >> 16)), we, acc1);
        }
    }
    int cnt = end - k0;
    if (cnt > 0) {
        int s = (i16 < cnt) ? csr[k0 + i16] : wid;
        float w = (i16 < cnt) ? __expf(lrelu02(as1[s * 4 + hh] + adh) - mh) : 0.f;
        den += w;
        for (int e = 0; e < cnt; ++e) {
            int se = __builtin_amdgcn_readlane(s, e);
            float we = __shfl(w, e, 16);
            unsigned int pv = *(const unsigned int*)(hb + (size_t)se * 128);
            acc0 = fmaf(bf2f((unsigned short)pv), we, acc0);
            acc1 = fmaf(bf2f((unsigned short)(pv >> 16)), we, acc1);
        }
    }
    // den: each lane holds its stripe; sum across the 16 lanes of this head group
    den += __shfl_xor(den, 1); den += __shfl_xor(den, 2);
    den += __shfl_xor(den, 4); den += __shfl_xor(den, 8);
    const float rden = 1.f / (den + 1e-16f);
    float v0 = acc0 * rden + b1[lane * 2];
    float v1 = acc1 * rden + b1[lane * 2 + 1];
    v0 = v0 > 0.f ? v0 : expm1f(v0);
    v1 = v1 > 0.f ? v1 : expm1f(v1);
    *(unsigned int*)(out1b + (size_t)wid * 128 + lane * 2) =
        f2bf(v0) | ((unsigned)f2bf(v1) << 16);
}

// ---------- layer-2 dense: g = out1 @ W2 (+ attn dots), H=1 C=8, bf16 input ----------
__global__ __launch_bounds__(256) void gemm2_k(
    const unsigned short* __restrict__ h2b, const float* __restrict__ W2,
    const float* __restrict__ aw_s, const float* __restrict__ aw_d,
    float* __restrict__ g, float* __restrict__ as2, float* __restrict__ ad2, int N)
{
    __shared__ float W2l[128 * 8];
    __shared__ float rows[32][129];
    for (int i = threadIdx.x; i < 128 * 8; i += 256) W2l[i] = W2[i];
    const int r = threadIdx.x >> 3, j = threadIdx.x & 7;
    const float ws_ = aw_s[j], wd_ = aw_d[j];
    for (int base = blockIdx.x * 32; base < N; base += gridDim.x * 32) {
        __syncthreads();
        for (int i = threadIdx.x; i < 32 * 64; i += 256) {
            int rr = i >> 6, kp = i & 63;
            int n = base + rr;
            unsigned int pv = (n < N) ? *(const unsigned int*)(h2b + (size_t)n * 128 + kp * 2) : 0u;
            rows[rr][kp * 2]     = bf2f((unsigned short)pv);
            rows[rr][kp * 2 + 1] = bf2f((unsigned short)(pv >> 16));
        }
        __syncthreads();
        int n = base + r;
        float acc = 0.f;
        #pragma unroll
        for (int k = 0; k < 128; ++k) acc += rows[r][k] * W2l[k * 8 + j];
        if (n < N) {
            g[n * 8 + j] = acc;
            float s = acc * ws_, d = acc * wd_;
            #pragma unroll
            for (int off = 4; off; off >>= 1) {
                s += __shfl_down(s, off, 8);
                d += __shfl_down(d, off, 8);
            }
            if (j == 0) { as2[n] = s; ad2[n] = d; }
        }
    }
}

// ---------- layer-2 single-pass softmax+aggregate+epilogue: one wave per dst ----------
// Chunk of 8 edges: all lanes compute w for edge (lane&7); the 8 lane-groups then each
// accumulate a different edge of the chunk (8 edges handled in ONE step).
__global__ __launch_bounds__(256) void gat2_k(
    const int* __restrict__ csr, const int* __restrict__ rowptr,
    const float* __restrict__ as2, const float* __restrict__ ad2,
    const float* __restrict__ g, const float* __restrict__ b2_,
    const float* __restrict__ Wlin, const float* __restrict__ blin,
    float* __restrict__ out, int N)
{
    const int wid  = (blockIdx.x * 256 + threadIdx.x) >> 6;
    const int lane = threadIdx.x & 63;
    if (wid >= N) return;
    const int start = rowptr[wid], end = rowptr[wid + 1];
    const int i8  = lane & 7;     // channel, and edge-slot for w-compute
    const int grp = lane >> 3;    // which edge of the chunk this group accumulates
    const float adh = ad2[wid];
    const float mh  = lrelu02(as2[wid] + adh);
    float den = 0.f, acc = 0.f;
    int k0 = start;
    for (; k0 + 8 <= end; k0 += 8) {
        int s = csr[k0 + i8];
        float w = __expf(lrelu02(as2[s] + adh) - mh);
        den += w;
        int   se = __shfl(s, grp, 8);   // edge grp of this chunk (from lane grp of my.. any group)
        float we = __shfl(w, grp, 8);
        acc = fmaf(we, g[(size_t)se * 8 + i8], acc);
    }
    int cnt = end - k0;
    if (cnt > 0) {
        int s = (i8 < cnt) ? csr[k0 + i8] : wid;
        float w = (i8 < cnt) ? __expf(lrelu02(as2[s] + adh) - mh) : 0.f;
        den += w;
        int   se = __shfl(s, grp, 8);
        float we = __shfl(w, grp, 8);
        acc = fmaf(we, g[(size_t)se * 8 + i8], acc);
    }
    // den: stripes live on the 8 lanes of each group (identical across groups)
    den += __shfl_xor(den, 1); den += __shfl_xor(den, 2); den += __shfl_xor(den, 4);
    // acc: same channel i8 distributed across the 8 groups
    acc += __shfl_xor(acc, 8); acc += __shfl_xor(acc, 16); acc += __shfl_xor(acc, 32);
    float v = acc / (den + 1e-16f) + b2_[i8];
    v = v > 0.f ? v : expm1f(v);
    float t = v * Wlin[i8];
    t += __shfl_xor(t, 1); t += __shfl_xor(t, 2); t += __shfl_xor(t, 4);
    if (lane == 0) out[wid] = 1.f / (1.f + __expf(-(t + blin[0])));
}

extern "C" void kernel_launch(void* const* d_in, const int* in_sizes, int n_in,
                              void* d_out, int out_size, void* d_ws, size_t ws_size,
                              hipStream_t stream)
{
    (void)n_in; (void)out_size; (void)ws_size;
    const float* x    = (const float*)d_in[0];
    const int*   ei   = (const int*)d_in[1];
    // d_in[2] = edge_attr, ignored
    const float* W1   = (const float*)d_in[3];
    const float* as1w = (const float*)d_in[4];
    const float* ad1w = (const float*)d_in[5];
    const float* b1   = (const float*)d_in[6];
    const float* W2   = (const float*)d_in[7];
    const float* as2w = (const float*)d_in[8];
    const float* ad2w = (const float*)d_in[9];
    const float* b2v  = (const float*)d_in[10];
    const float* Wlin = (const float*)d_in[11];
    const float* blin = (const float*)d_in[12];

    const int N = in_sizes[0] / 128;
    const int E = in_sizes[1] / 2;
    const int total = E + N;

    // workspace layout
    float* p = (float*)d_ws;
    unsigned short* h1b   = (unsigned short*)p; p += (size_t)N * 64;  // N*128 bf16
    unsigned short* out1b = (unsigned short*)p; p += (size_t)N * 64;
    float* as1  = p; p += (size_t)N * 4;
    float* ad1  = p; p += (size_t)N * 4;
    float* g    = p; p += (size_t)N * 8;
    float* as2  = p; p += (size_t)N;
    float* ad2  = p; p += (size_t)N;
    int* deg    = (int*)p; p += (size_t)N;
    int* rowptr = (int*)p; p += (size_t)N + 1;
    int* cursor = (int*)p; p += (size_t)N;
    int* bsum   = (int*)p; p += ((size_t)N + 255) / 256;
    int* csr    = (int*)p; p += (size_t)total;

    const int eb = (total + 255) / 256;
    const int nb = (N + 255) / 256;

    hipMemsetAsync(deg, 0, (size_t)N * sizeof(int), stream);
    gemm1_k<<<(N + 63) / 64, 256, 0, stream>>>(x, W1, as1w, ad1w, h1b, as1, ad1, N);
    degcnt_k<<<eb, 256, 0, stream>>>(ei, E, N, deg);
    blocksum_k<<<nb, 256, 0, stream>>>(deg, N, bsum);
    scanbsum_k<<<1, 1024, 0, stream>>>(bsum, nb);
    rowptr_k<<<nb, 256, 0, stream>>>(deg, bsum, N, E, rowptr, cursor);
    fill_k<<<eb, 256, 0, stream>>>(ei, E, N, cursor, csr);

    // layer 1: single-pass softmax + aggregate + bias + ELU
    gat1_k<<<(N * 64 + 255) / 256, 256, 0, stream>>>(csr, rowptr, as1, ad1, h1b, b1, out1b, N);

    // layer 2
    gemm2_k<<<3125, 256, 0, stream>>>(out1b, W2, as2w, ad2w, g, as2, ad2, N);
    gat2_k<<<(N * 64 + 255) / 256, 256, 0, stream>>>(csr, rowptr, as2, ad2, g, b2v, Wlin, blin,
                                                     (float*)d_out, N);
}

// Round 7
// 486.463 us; speedup vs baseline: 4.0137x; 1.1183x over previous
//
#include <hip/hip_runtime.h>
#include <hip/hip_bf16.h>

__device__ __forceinline__ float lrelu02(float v) { return v > 0.f ? v : 0.2f * v; }

// manual bf16 <-> f32 (RNE); finite data only
__device__ __forceinline__ float bf2f(unsigned short u) {
    union { unsigned int i; float f; } v; v.i = ((unsigned int)u) << 16; return v.f;
}
__device__ __forceinline__ unsigned short f2bf(float f) {
    union { float f; unsigned int i; } v; v.f = f;
    unsigned int x = v.i;
    return (unsigned short)((x + 0x7fffu + ((x >> 16) & 1u)) >> 16);
}

// ---------- layer-1 dense: h1 = x @ W1 (+ fused attn dots), register-tiled ----------
__global__ __launch_bounds__(256) void gemm1_k(
    const float* __restrict__ x, const float* __restrict__ W1,
    const float* __restrict__ aw_s, const float* __restrict__ aw_d,
    unsigned short* __restrict__ h1b, float* __restrict__ as1, float* __restrict__ ad1, int N)
{
    __shared__ float Wl[128 * 128];   // 64 KB
    for (int i = threadIdx.x; i < 128 * 128 / 4; i += 256)
        ((float4*)Wl)[i] = ((const float4*)W1)[i];

    const int cl = threadIdx.x & 15;
    const int rg = threadIdx.x >> 4;
    const int head = cl >> 2;
    const int row0 = blockIdx.x * 64 + rg * 4;
    __syncthreads();

    const float4* x4[4];
    bool rv[4];
    #pragma unroll
    for (int r = 0; r < 4; ++r) {
        int rr = row0 + r;
        rv[r] = rr < N;
        int rc = rv[r] ? rr : (N - 1);
        x4[r] = (const float4*)(x + (size_t)rc * 128);
    }

    float acc[4][8];
    #pragma unroll
    for (int r = 0; r < 4; ++r)
        #pragma unroll
        for (int c = 0; c < 8; ++c) acc[r][c] = 0.f;

    for (int k4 = 0; k4 < 32; ++k4) {
        float4 xv[4];
        #pragma unroll
        for (int r = 0; r < 4; ++r) xv[r] = x4[r][k4];
        #pragma unroll
        for (int kk = 0; kk < 4; ++kk) {
            const int k = k4 * 4 + kk;
            const float4 w0 = *(const float4*)(Wl + k * 128 + cl * 8);
            const float4 w1 = *(const float4*)(Wl + k * 128 + cl * 8 + 4);
            #pragma unroll
            for (int r = 0; r < 4; ++r) {
                const float xk = kk == 0 ? xv[r].x : kk == 1 ? xv[r].y : kk == 2 ? xv[r].z : xv[r].w;
                acc[r][0] = fmaf(xk, w0.x, acc[r][0]);
                acc[r][1] = fmaf(xk, w0.y, acc[r][1]);
                acc[r][2] = fmaf(xk, w0.z, acc[r][2]);
                acc[r][3] = fmaf(xk, w0.w, acc[r][3]);
                acc[r][4] = fmaf(xk, w1.x, acc[r][4]);
                acc[r][5] = fmaf(xk, w1.y, acc[r][5]);
                acc[r][6] = fmaf(xk, w1.z, acc[r][6]);
                acc[r][7] = fmaf(xk, w1.w, acc[r][7]);
            }
        }
    }

    float ws_[8], wd_[8];
    #pragma unroll
    for (int c = 0; c < 8; ++c) { ws_[c] = aw_s[cl * 8 + c]; wd_[c] = aw_d[cl * 8 + c]; }

    #pragma unroll
    for (int r = 0; r < 4; ++r) {
        float s = 0.f, d = 0.f;
        #pragma unroll
        for (int c = 0; c < 8; ++c) { s = fmaf(acc[r][c], ws_[c], s); d = fmaf(acc[r][c], wd_[c], d); }
        s += __shfl_xor(s, 1); s += __shfl_xor(s, 2);
        d += __shfl_xor(d, 1); d += __shfl_xor(d, 2);
        if (rv[r]) {
            if ((cl & 3) == 0) { as1[(row0 + r) * 4 + head] = s; ad1[(row0 + r) * 4 + head] = d; }
            uint4 pk;
            pk.x = f2bf(acc[r][0]) | ((unsigned)f2bf(acc[r][1]) << 16);
            pk.y = f2bf(acc[r][2]) | ((unsigned)f2bf(acc[r][3]) << 16);
            pk.z = f2bf(acc[r][4]) | ((unsigned)f2bf(acc[r][5]) << 16);
            pk.w = f2bf(acc[r][6]) | ((unsigned)f2bf(acc[r][7]) << 16);
            *(uint4*)(h1b + (size_t)(row0 + r) * 128 + cl * 8) = pk;
        }
    }
}

// ---------- CSR build ----------
// Pass 1: one atomic does BOTH degree count and per-edge rank assignment.
__global__ __launch_bounds__(256) void rank_k(
    const int* __restrict__ ei, int E, int N,
    int* __restrict__ deg, int* __restrict__ rank)
{
    int e = blockIdx.x * 256 + threadIdx.x;
    if (e >= E + N) return;
    int d = (e < E) ? ei[E + e] : (e - E);
    rank[e] = atomicAdd(&deg[d], 1);
}

__global__ __launch_bounds__(256) void blocksum_k(
    const int* __restrict__ deg, int N, int* __restrict__ bsum)
{
    __shared__ int sh[256];
    int i = blockIdx.x * 256 + threadIdx.x;
    sh[threadIdx.x] = (i < N) ? deg[i] : 0;
    __syncthreads();
    for (int off = 128; off; off >>= 1) {
        if (threadIdx.x < off) sh[threadIdx.x] += sh[threadIdx.x + off];
        __syncthreads();
    }
    if (threadIdx.x == 0) bsum[blockIdx.x] = sh[0];
}

__global__ __launch_bounds__(1024) void scanbsum_k(int* __restrict__ bsum, int nb)
{
    __shared__ int buf[1024];
    __shared__ int carry;
    if (threadIdx.x == 0) carry = 0;
    __syncthreads();
    for (int base = 0; base < nb; base += 1024) {
        int i = base + threadIdx.x;
        int v = (i < nb) ? bsum[i] : 0;
        buf[threadIdx.x] = v;
        __syncthreads();
        for (int off = 1; off < 1024; off <<= 1) {
            int t = (threadIdx.x >= off) ? buf[threadIdx.x - off] : 0;
            __syncthreads();
            buf[threadIdx.x] += t;
            __syncthreads();
        }
        if (i < nb) bsum[i] = buf[threadIdx.x] - v + carry;   // exclusive
        __syncthreads();
        if (threadIdx.x == 0) carry += buf[1023];
        __syncthreads();
    }
}

__global__ __launch_bounds__(256) void rowptr_k(
    const int* __restrict__ deg, const int* __restrict__ bsum, int N, int E,
    int* __restrict__ rowptr)
{
    __shared__ int buf[256];
    int i = blockIdx.x * 256 + threadIdx.x;
    int v = (i < N) ? deg[i] : 0;
    buf[threadIdx.x] = v;
    __syncthreads();
    for (int off = 1; off < 256; off <<= 1) {
        int t = (threadIdx.x >= off) ? buf[threadIdx.x - off] : 0;
        __syncthreads();
        buf[threadIdx.x] += t;
        __syncthreads();
    }
    if (i < N) rowptr[i] = bsum[blockIdx.x] + buf[threadIdx.x] - v;
    if (i == 0) rowptr[N] = E + N;
}

// Pass 2: pure scatter, no atomic (rank already known).
__global__ __launch_bounds__(256) void place_k(
    const int* __restrict__ ei, int E, int N,
    const int* __restrict__ rank, const int* __restrict__ rowptr,
    int* __restrict__ csr)
{
    int e = blockIdx.x * 256 + threadIdx.x;
    if (e >= E + N) return;
    int s, d;
    if (e < E) { s = ei[e]; d = ei[E + e]; } else { s = d = e - E; }
    csr[rowptr[d] + rank[e]] = s;
}

// ---------- layer-1 single-pass softmax-aggregate (+bias+ELU): one wave per dst ----------
__global__ __launch_bounds__(256) void gat1_k(
    const int* __restrict__ csr, const int* __restrict__ rowptr,
    const float* __restrict__ as1, const float* __restrict__ ad1,
    const unsigned short* __restrict__ h1b, const float* __restrict__ b1,
    unsigned short* __restrict__ out1b, int N)
{
    const int wid  = (blockIdx.x * 256 + threadIdx.x) >> 6;
    const int lane = threadIdx.x & 63;
    if (wid >= N) return;
    const int start = rowptr[wid], end = rowptr[wid + 1];
    const int i16 = lane & 15;        // edge slot within chunk
    const int hh  = lane >> 4;        // head for w-compute AND for my channels
    const float adh = ad1[wid * 4 + hh];
    const float mh  = lrelu02(as1[wid * 4 + hh] + adh);   // self-logit offset (den >= 1)
    const unsigned short* hb = h1b + lane * 2;

    float den = 0.f, acc0 = 0.f, acc1 = 0.f;
    int k0 = start;
    for (; k0 + 16 <= end; k0 += 16) {
        int s = csr[k0 + i16];
        float w = __expf(lrelu02(as1[s * 4 + hh] + adh) - mh);
        den += w;
        #pragma unroll
        for (int e = 0; e < 16; ++e) {
            int se = __builtin_amdgcn_readlane(s, e);          // uniform -> scalar base
            float we = __shfl(w, e, 16);                       // per-head broadcast
            unsigned int pv = *(const unsigned int*)(hb + (size_t)se * 128);
            acc0 = fmaf(bf2f((unsigned short)pv), we, acc0);
            acc1 = fmaf(bf2f((unsigned short)(pv >> 16)), we, acc1);
        }
    }
    int cnt = end - k0;
    if (cnt > 0) {
        int s = (i16 < cnt) ? csr[k0 + i16] : wid;
        float w = (i16 < cnt) ? __expf(lrelu02(as1[s * 4 + hh] + adh) - mh) : 0.f;
        den += w;
        for (int e = 0; e < cnt; ++e) {
            int se = __builtin_amdgcn_readlane(s, e);
            float we = __shfl(w, e, 16);
            unsigned int pv = *(const unsigned int*)(hb + (size_t)se * 128);
            acc0 = fmaf(bf2f((unsigned short)pv), we, acc0);
            acc1 = fmaf(bf2f((unsigned short)(pv >> 16)), we, acc1);
        }
    }
    den += __shfl_xor(den, 1); den += __shfl_xor(den, 2);
    den += __shfl_xor(den, 4); den += __shfl_xor(den, 8);
    const float rden = 1.f / (den + 1e-16f);
    float v0 = acc0 * rden + b1[lane * 2];
    float v1 = acc1 * rden + b1[lane * 2 + 1];
    v0 = v0 > 0.f ? v0 : expm1f(v0);
    v1 = v1 > 0.f ? v1 : expm1f(v1);
    *(unsigned int*)(out1b + (size_t)wid * 128 + lane * 2) =
        f2bf(v0) | ((unsigned)f2bf(v1) << 16);
}

// ---------- layer-2 dense: g = out1 @ W2 (+ attn dots), H=1 C=8, bf16 input ----------
__global__ __launch_bounds__(256) void gemm2_k(
    const unsigned short* __restrict__ h2b, const float* __restrict__ W2,
    const float* __restrict__ aw_s, const float* __restrict__ aw_d,
    float* __restrict__ g, float* __restrict__ as2, float* __restrict__ ad2, int N)
{
    __shared__ float W2l[128 * 8];
    __shared__ float rows[32][129];
    for (int i = threadIdx.x; i < 128 * 8; i += 256) W2l[i] = W2[i];
    const int r = threadIdx.x >> 3, j = threadIdx.x & 7;
    const float ws_ = aw_s[j], wd_ = aw_d[j];
    for (int base = blockIdx.x * 32; base < N; base += gridDim.x * 32) {
        __syncthreads();
        for (int i = threadIdx.x; i < 32 * 64; i += 256) {
            int rr = i >> 6, kp = i & 63;
            int n = base + rr;
            unsigned int pv = (n < N) ? *(const unsigned int*)(h2b + (size_t)n * 128 + kp * 2) : 0u;
            rows[rr][kp * 2]     = bf2f((unsigned short)pv);
            rows[rr][kp * 2 + 1] = bf2f((unsigned short)(pv >> 16));
        }
        __syncthreads();
        int n = base + r;
        float acc = 0.f;
        #pragma unroll
        for (int k = 0; k < 128; ++k) acc += rows[r][k] * W2l[k * 8 + j];
        if (n < N) {
            g[n * 8 + j] = acc;
            float s = acc * ws_, d = acc * wd_;
            #pragma unroll
            for (int off = 4; off; off >>= 1) {
                s += __shfl_down(s, off, 8);
                d += __shfl_down(d, off, 8);
            }
            if (j == 0) { as2[n] = s; ad2[n] = d; }
        }
    }
}

// ---------- layer-2 single-pass softmax+aggregate+epilogue: one wave per dst ----------
__global__ __launch_bounds__(256) void gat2_k(
    const int* __restrict__ csr, const int* __restrict__ rowptr,
    const float* __restrict__ as2, const float* __restrict__ ad2,
    const float* __restrict__ g, const float* __restrict__ b2_,
    const float* __restrict__ Wlin, const float* __restrict__ blin,
    float* __restrict__ out, int N)
{
    const int wid  = (blockIdx.x * 256 + threadIdx.x) >> 6;
    const int lane = threadIdx.x & 63;
    if (wid >= N) return;
    const int start = rowptr[wid], end = rowptr[wid + 1];
    const int i8  = lane & 7;     // channel, and edge-slot for w-compute
    const int grp = lane >> 3;    // which edge of the chunk this group accumulates
    const float adh = ad2[wid];
    const float mh  = lrelu02(as2[wid] + adh);
    float den = 0.f, acc = 0.f;
    int k0 = start;
    for (; k0 + 8 <= end; k0 += 8) {
        int s = csr[k0 + i8];
        float w = __expf(lrelu02(as2[s] + adh) - mh);
        den += w;
        int   se = __shfl(s, grp, 8);
        float we = __shfl(w, grp, 8);
        acc = fmaf(we, g[(size_t)se * 8 + i8], acc);
    }
    int cnt = end - k0;
    if (cnt > 0) {
        int s = (i8 < cnt) ? csr[k0 + i8] : wid;
        float w = (i8 < cnt) ? __expf(lrelu02(as2[s] + adh) - mh) : 0.f;
        den += w;
        int   se = __shfl(s, grp, 8);
        float we = __shfl(w, grp, 8);
        acc = fmaf(we, g[(size_t)se * 8 + i8], acc);
    }
    den += __shfl_xor(den, 1); den += __shfl_xor(den, 2); den += __shfl_xor(den, 4);
    acc += __shfl_xor(acc, 8); acc += __shfl_xor(acc, 16); acc += __shfl_xor(acc, 32);
    float v = acc / (den + 1e-16f) + b2_[i8];
    v = v > 0.f ? v : expm1f(v);
    float t = v * Wlin[i8];
    t += __shfl_xor(t, 1); t += __shfl_xor(t, 2); t += __shfl_xor(t, 4);
    if (lane == 0) out[wid] = 1.f / (1.f + __expf(-(t + blin[0])));
}

extern "C" void kernel_launch(void* const* d_in, const int* in_sizes, int n_in,
                              void* d_out, int out_size, void* d_ws, size_t ws_size,
                              hipStream_t stream)
{
    (void)n_in; (void)out_size; (void)ws_size;
    const float* x    = (const float*)d_in[0];
    const int*   ei   = (const int*)d_in[1];
    // d_in[2] = edge_attr, ignored
    const float* W1   = (const float*)d_in[3];
    const float* as1w = (const float*)d_in[4];
    const float* ad1w = (const float*)d_in[5];
    const float* b1   = (const float*)d_in[6];
    const float* W2   = (const float*)d_in[7];
    const float* as2w = (const float*)d_in[8];
    const float* ad2w = (const float*)d_in[9];
    const float* b2v  = (const float*)d_in[10];
    const float* Wlin = (const float*)d_in[11];
    const float* blin = (const float*)d_in[12];

    const int N = in_sizes[0] / 128;
    const int E = in_sizes[1] / 2;
    const int total = E + N;

    // workspace layout
    float* p = (float*)d_ws;
    unsigned short* h1b   = (unsigned short*)p; p += (size_t)N * 64;  // N*128 bf16
    unsigned short* out1b = (unsigned short*)p; p += (size_t)N * 64;
    float* as1  = p; p += (size_t)N * 4;
    float* ad1  = p; p += (size_t)N * 4;
    float* g    = p; p += (size_t)N * 8;
    float* as2  = p; p += (size_t)N;
    float* ad2  = p; p += (size_t)N;
    int* deg    = (int*)p; p += (size_t)N;
    int* rowptr = (int*)p; p += (size_t)N + 1;
    int* bsum   = (int*)p; p += ((size_t)N + 255) / 256;
    int* rank   = (int*)p; p += (size_t)total;
    int* csr    = (int*)p; p += (size_t)total;

    const int eb = (total + 255) / 256;
    const int nb = (N + 255) / 256;

    hipMemsetAsync(deg, 0, (size_t)N * sizeof(int), stream);
    gemm1_k<<<(N + 63) / 64, 256, 0, stream>>>(x, W1, as1w, ad1w, h1b, as1, ad1, N);
    rank_k<<<eb, 256, 0, stream>>>(ei, E, N, deg, rank);
    blocksum_k<<<nb, 256, 0, stream>>>(deg, N, bsum);
    scanbsum_k<<<1, 1024, 0, stream>>>(bsum, nb);
    rowptr_k<<<nb, 256, 0, stream>>>(deg, bsum, N, E, rowptr);
    place_k<<<eb, 256, 0, stream>>>(ei, E, N, rank, rowptr, csr);

    // layer 1: single-pass softmax + aggregate + bias + ELU
    gat1_k<<<(N * 64 + 255) / 256, 256, 0, stream>>>(csr, rowptr, as1, ad1, h1b, b1, out1b, N);

    // layer 2
    gemm2_k<<<3125, 256, 0, stream>>>(out1b, W2, as2w, ad2w, g, as2, ad2, N);
    gat2_k<<<(N * 64 + 255) / 256, 256, 0, stream>>>(csr, rowptr, as2, ad2, g, b2v, Wlin, blin,
                                                     (float*)d_out, N);
}

// Round 8
// 447.009 us; speedup vs baseline: 4.3680x; 1.0883x over previous
//
#include <hip/hip_runtime.h>
#include <hip/hip_bf16.h>

__device__ __forceinline__ float lrelu02(float v) { return v > 0.f ? v : 0.2f * v; }

// manual bf16 <-> f32 (RNE); finite data only
__device__ __forceinline__ float bf2f(unsigned short u) {
    union { unsigned int i; float f; } v; v.i = ((unsigned int)u) << 16; return v.f;
}
__device__ __forceinline__ unsigned short f2bf(float f) {
    union { float f; unsigned int i; } v; v.f = f;
    unsigned int x = v.i;
    return (unsigned short)((x + 0x7fffu + ((x >> 16) & 1u)) >> 16);
}

// ---------- fused: CSR rank pass + layer-1 dense (h1 = x @ W1 + attn dots) ----------
// The rank slice is latency-bound (random atomicAdd); the GEMM is compute-bound.
// Fused in one kernel the atomic round-trips hide under the FMA stream.
__global__ __launch_bounds__(256) void gemm1_k(
    const float* __restrict__ x, const float* __restrict__ W1,
    const float* __restrict__ aw_s, const float* __restrict__ aw_d,
    unsigned short* __restrict__ h1b, float* __restrict__ as1, float* __restrict__ ad1, int N,
    const int* __restrict__ ei, int E, int* __restrict__ deg, int* __restrict__ rank)
{
    // --- rank slice (grid-stride over E+N edges) ---
    {
        const int total = E + N;
        const int stride = gridDim.x * 256;
        for (int e = blockIdx.x * 256 + threadIdx.x; e < total; e += stride) {
            int d = (e < E) ? ei[E + e] : (e - E);
            rank[e] = atomicAdd(&deg[d], 1);
        }
    }

    // --- GEMM tile ---
    __shared__ float Wl[128 * 128];   // 64 KB
    for (int i = threadIdx.x; i < 128 * 128 / 4; i += 256)
        ((float4*)Wl)[i] = ((const float4*)W1)[i];

    const int cl = threadIdx.x & 15;
    const int rg = threadIdx.x >> 4;
    const int head = cl >> 2;
    const int row0 = blockIdx.x * 64 + rg * 4;
    __syncthreads();

    const float4* x4[4];
    bool rv[4];
    #pragma unroll
    for (int r = 0; r < 4; ++r) {
        int rr = row0 + r;
        rv[r] = rr < N;
        int rc = rv[r] ? rr : (N - 1);
        x4[r] = (const float4*)(x + (size_t)rc * 128);
    }

    float acc[4][8];
    #pragma unroll
    for (int r = 0; r < 4; ++r)
        #pragma unroll
        for (int c = 0; c < 8; ++c) acc[r][c] = 0.f;

    for (int k4 = 0; k4 < 32; ++k4) {
        float4 xv[4];
        #pragma unroll
        for (int r = 0; r < 4; ++r) xv[r] = x4[r][k4];
        #pragma unroll
        for (int kk = 0; kk < 4; ++kk) {
            const int k = k4 * 4 + kk;
            const float4 w0 = *(const float4*)(Wl + k * 128 + cl * 8);
            const float4 w1 = *(const float4*)(Wl + k * 128 + cl * 8 + 4);
            #pragma unroll
            for (int r = 0; r < 4; ++r) {
                const float xk = kk == 0 ? xv[r].x : kk == 1 ? xv[r].y : kk == 2 ? xv[r].z : xv[r].w;
                acc[r][0] = fmaf(xk, w0.x, acc[r][0]);
                acc[r][1] = fmaf(xk, w0.y, acc[r][1]);
                acc[r][2] = fmaf(xk, w0.z, acc[r][2]);
                acc[r][3] = fmaf(xk, w0.w, acc[r][3]);
                acc[r][4] = fmaf(xk, w1.x, acc[r][4]);
                acc[r][5] = fmaf(xk, w1.y, acc[r][5]);
                acc[r][6] = fmaf(xk, w1.z, acc[r][6]);
                acc[r][7] = fmaf(xk, w1.w, acc[r][7]);
            }
        }
    }

    float ws_[8], wd_[8];
    #pragma unroll
    for (int c = 0; c < 8; ++c) { ws_[c] = aw_s[cl * 8 + c]; wd_[c] = aw_d[cl * 8 + c]; }

    #pragma unroll
    for (int r = 0; r < 4; ++r) {
        float s = 0.f, d = 0.f;
        #pragma unroll
        for (int c = 0; c < 8; ++c) { s = fmaf(acc[r][c], ws_[c], s); d = fmaf(acc[r][c], wd_[c], d); }
        s += __shfl_xor(s, 1); s += __shfl_xor(s, 2);
        d += __shfl_xor(d, 1); d += __shfl_xor(d, 2);
        if (rv[r]) {
            if ((cl & 3) == 0) { as1[(row0 + r) * 4 + head] = s; ad1[(row0 + r) * 4 + head] = d; }
            uint4 pk;
            pk.x = f2bf(acc[r][0]) | ((unsigned)f2bf(acc[r][1]) << 16);
            pk.y = f2bf(acc[r][2]) | ((unsigned)f2bf(acc[r][3]) << 16);
            pk.z = f2bf(acc[r][4]) | ((unsigned)f2bf(acc[r][5]) << 16);
            pk.w = f2bf(acc[r][6]) | ((unsigned)f2bf(acc[r][7]) << 16);
            *(uint4*)(h1b + (size_t)(row0 + r) * 128 + cl * 8) = pk;
        }
    }
}

// ---------- CSR scan ----------
__global__ __launch_bounds__(256) void blocksum_k(
    const int* __restrict__ deg, int N, int* __restrict__ bsum)
{
    __shared__ int sh[256];
    int i = blockIdx.x * 256 + threadIdx.x;
    sh[threadIdx.x] = (i < N) ? deg[i] : 0;
    __syncthreads();
    for (int off = 128; off; off >>= 1) {
        if (threadIdx.x < off) sh[threadIdx.x] += sh[threadIdx.x + off];
        __syncthreads();
    }
    if (threadIdx.x == 0) bsum[blockIdx.x] = sh[0];
}

__global__ __launch_bounds__(1024) void scanbsum_k(int* __restrict__ bsum, int nb)
{
    __shared__ int buf[1024];
    __shared__ int carry;
    if (threadIdx.x == 0) carry = 0;
    __syncthreads();
    for (int base = 0; base < nb; base += 1024) {
        int i = base + threadIdx.x;
        int v = (i < nb) ? bsum[i] : 0;
        buf[threadIdx.x] = v;
        __syncthreads();
        for (int off = 1; off < 1024; off <<= 1) {
            int t = (threadIdx.x >= off) ? buf[threadIdx.x - off] : 0;
            __syncthreads();
            buf[threadIdx.x] += t;
            __syncthreads();
        }
        if (i < nb) bsum[i] = buf[threadIdx.x] - v + carry;   // exclusive
        __syncthreads();
        if (threadIdx.x == 0) carry += buf[1023];
        __syncthreads();
    }
}

__global__ __launch_bounds__(256) void rowptr_k(
    const int* __restrict__ deg, const int* __restrict__ bsum, int N, int E,
    int* __restrict__ rowptr)
{
    __shared__ int buf[256];
    int i = blockIdx.x * 256 + threadIdx.x;
    int v = (i < N) ? deg[i] : 0;
    buf[threadIdx.x] = v;
    __syncthreads();
    for (int off = 1; off < 256; off <<= 1) {
        int t = (threadIdx.x >= off) ? buf[threadIdx.x - off] : 0;
        __syncthreads();
        buf[threadIdx.x] += t;
        __syncthreads();
    }
    if (i < N) rowptr[i] = bsum[blockIdx.x] + buf[threadIdx.x] - v;
    if (i == 0) rowptr[N] = E + N;
}

// Pure scatter, no atomic (rank already known).
__global__ __launch_bounds__(256) void place_k(
    const int* __restrict__ ei, int E, int N,
    const int* __restrict__ rank, const int* __restrict__ rowptr,
    int* __restrict__ csr)
{
    int e = blockIdx.x * 256 + threadIdx.x;
    if (e >= E + N) return;
    int s, d;
    if (e < E) { s = ei[e]; d = ei[E + e]; } else { s = d = e - E; }
    csr[rowptr[d] + rank[e]] = s;
}

// ---------- layer-1 fused: softmax-aggregate + bias + ELU + gemm2 + attn2 dots ----------
// One wave per dst node. out1 row never hits global memory.
__global__ __launch_bounds__(256) void gat1_k(
    const int* __restrict__ csr, const int* __restrict__ rowptr,
    const float* __restrict__ as1, const float* __restrict__ ad1,
    const unsigned short* __restrict__ h1b, const float* __restrict__ b1,
    const float* __restrict__ W2, const float* __restrict__ aw_s2, const float* __restrict__ aw_d2,
    float* __restrict__ g, float* __restrict__ as2, float* __restrict__ ad2, int N)
{
    __shared__ float red[4][8][12];   // [wave][src-lane][j] (+pad: 48B stride, b128-aligned)
    const int wv   = threadIdx.x >> 6;
    const int wid  = (blockIdx.x * 256 + threadIdx.x) >> 6;
    const int lane = threadIdx.x & 63;
    if (wid >= N) return;
    const int start = rowptr[wid], end = rowptr[wid + 1];
    const int i16 = lane & 15;        // edge slot within chunk
    const int hh  = lane >> 4;        // head for w-compute AND for my channels
    const float adh = ad1[wid * 4 + hh];
    const float mh  = lrelu02(as1[wid * 4 + hh] + adh);   // self-logit offset (den >= 1)
    const unsigned short* hb = h1b + lane * 2;

    float den = 0.f, acc0 = 0.f, acc1 = 0.f;
    int k0 = start;
    for (; k0 + 16 <= end; k0 += 16) {
        int s = csr[k0 + i16];
        float w = __expf(lrelu02(as1[s * 4 + hh] + adh) - mh);
        den += w;
        #pragma unroll
        for (int e = 0; e < 16; ++e) {
            int se = __builtin_amdgcn_readlane(s, e);          // uniform -> scalar base
            float we = __shfl(w, e, 16);                       // per-head broadcast
            unsigned int pv = *(const unsigned int*)(hb + (size_t)se * 128);
            acc0 = fmaf(bf2f((unsigned short)pv), we, acc0);
            acc1 = fmaf(bf2f((unsigned short)(pv >> 16)), we, acc1);
        }
    }
    int cnt = end - k0;
    if (cnt > 0) {
        int s = (i16 < cnt) ? csr[k0 + i16] : wid;
        float w = (i16 < cnt) ? __expf(lrelu02(as1[s * 4 + hh] + adh) - mh) : 0.f;
        den += w;
        for (int e = 0; e < cnt; ++e) {
            int se = __builtin_amdgcn_readlane(s, e);
            float we = __shfl(w, e, 16);
            unsigned int pv = *(const unsigned int*)(hb + (size_t)se * 128);
            acc0 = fmaf(bf2f((unsigned short)pv), we, acc0);
            acc1 = fmaf(bf2f((unsigned short)(pv >> 16)), we, acc1);
        }
    }
    den += __shfl_xor(den, 1); den += __shfl_xor(den, 2);
    den += __shfl_xor(den, 4); den += __shfl_xor(den, 8);
    const float rden = 1.f / (den + 1e-16f);
    float v0 = acc0 * rden + b1[lane * 2];
    float v1 = acc1 * rden + b1[lane * 2 + 1];
    v0 = v0 > 0.f ? v0 : expm1f(v0);
    v1 = v1 > 0.f ? v1 : expm1f(v1);

    // --- fused gemm2: g_j = sum_k elu_out[k] * W2[k][j] (k = 2*lane, 2*lane+1) ---
    const float4 a0 = *(const float4*)(W2 + 16 * lane);
    const float4 a1 = *(const float4*)(W2 + 16 * lane + 4);
    const float4 b0 = *(const float4*)(W2 + 16 * lane + 8);
    const float4 b1v = *(const float4*)(W2 + 16 * lane + 12);
    float p[8];
    p[0] = v0 * a0.x + v1 * b0.x;  p[1] = v0 * a0.y + v1 * b0.y;
    p[2] = v0 * a0.z + v1 * b0.z;  p[3] = v0 * a0.w + v1 * b0.w;
    p[4] = v0 * a1.x + v1 * b1v.x; p[5] = v0 * a1.y + v1 * b1v.y;
    p[6] = v0 * a1.z + v1 * b1v.z; p[7] = v0 * a1.w + v1 * b1v.w;
    #pragma unroll
    for (int j = 0; j < 8; ++j) {
        p[j] += __shfl_xor(p[j], 8);
        p[j] += __shfl_xor(p[j], 16);
        p[j] += __shfl_xor(p[j], 32);
    }
    // lanes 0..7 now hold per-residue partials; 8x8 LDS transpose to finish
    if (lane < 8) {
        #pragma unroll
        for (int j = 0; j < 8; ++j) red[wv][lane][j] = p[j];
    }
    // same-wave LDS producer/consumer: DS ops are in-order within a wave
    if (lane < 8) {
        float gj = 0.f;
        #pragma unroll
        for (int c = 0; c < 8; ++c) gj += red[wv][c][lane];
        g[(size_t)wid * 8 + lane] = gj;
        float ts = gj * aw_s2[lane], td = gj * aw_d2[lane];
        ts += __shfl_xor(ts, 1); ts += __shfl_xor(ts, 2); ts += __shfl_xor(ts, 4);
        td += __shfl_xor(td, 1); td += __shfl_xor(td, 2); td += __shfl_xor(td, 4);
        if (lane == 0) { as2[wid] = ts; ad2[wid] = td; }
    }
}

// ---------- layer-2 single-pass softmax+aggregate+epilogue: one wave per dst ----------
__global__ __launch_bounds__(256) void gat2_k(
    const int* __restrict__ csr, const int* __restrict__ rowptr,
    const float* __restrict__ as2, const float* __restrict__ ad2,
    const float* __restrict__ g, const float* __restrict__ b2_,
    const float* __restrict__ Wlin, const float* __restrict__ blin,
    float* __restrict__ out, int N)
{
    const int wid  = (blockIdx.x * 256 + threadIdx.x) >> 6;
    const int lane = threadIdx.x & 63;
    if (wid >= N) return;
    const int start = rowptr[wid], end = rowptr[wid + 1];
    const int i8  = lane & 7;     // channel, and edge-slot for w-compute
    const int grp = lane >> 3;    // which edge of the chunk this group accumulates
    const float adh = ad2[wid];
    const float mh  = lrelu02(as2[wid] + adh);
    float den = 0.f, acc = 0.f;
    int k0 = start;
    for (; k0 + 8 <= end; k0 += 8) {
        int s = csr[k0 + i8];
        float w = __expf(lrelu02(as2[s] + adh) - mh);
        den += w;
        int   se = __shfl(s, grp, 8);
        float we = __shfl(w, grp, 8);
        acc = fmaf(we, g[(size_t)se * 8 + i8], acc);
    }
    int cnt = end - k0;
    if (cnt > 0) {
        int s = (i8 < cnt) ? csr[k0 + i8] : wid;
        float w = (i8 < cnt) ? __expf(lrelu02(as2[s] + adh) - mh) : 0.f;
        den += w;
        int   se = __shfl(s, grp, 8);
        float we = __shfl(w, grp, 8);
        acc = fmaf(we, g[(size_t)se * 8 + i8], acc);
    }
    den += __shfl_xor(den, 1); den += __shfl_xor(den, 2); den += __shfl_xor(den, 4);
    acc += __shfl_xor(acc, 8); acc += __shfl_xor(acc, 16); acc += __shfl_xor(acc, 32);
    float v = acc / (den + 1e-16f) + b2_[i8];
    v = v > 0.f ? v : expm1f(v);
    float t = v * Wlin[i8];
    t += __shfl_xor(t, 1); t += __shfl_xor(t, 2); t += __shfl_xor(t, 4);
    if (lane == 0) out[wid] = 1.f / (1.f + __expf(-(t + blin[0])));
}

extern "C" void kernel_launch(void* const* d_in, const int* in_sizes, int n_in,
                              void* d_out, int out_size, void* d_ws, size_t ws_size,
                              hipStream_t stream)
{
    (void)n_in; (void)out_size; (void)ws_size;
    const float* x    = (const float*)d_in[0];
    const int*   ei   = (const int*)d_in[1];
    // d_in[2] = edge_attr, ignored
    const float* W1   = (const float*)d_in[3];
    const float* as1w = (const float*)d_in[4];
    const float* ad1w = (const float*)d_in[5];
    const float* b1   = (const float*)d_in[6];
    const float* W2   = (const float*)d_in[7];
    const float* as2w = (const float*)d_in[8];
    const float* ad2w = (const float*)d_in[9];
    const float* b2v  = (const float*)d_in[10];
    const float* Wlin = (const float*)d_in[11];
    const float* blin = (const float*)d_in[12];

    const int N = in_sizes[0] / 128;
    const int E = in_sizes[1] / 2;
    const int total = E + N;

    // workspace layout
    float* p = (float*)d_ws;
    unsigned short* h1b = (unsigned short*)p; p += (size_t)N * 64;  // N*128 bf16
    float* as1  = p; p += (size_t)N * 4;
    float* ad1  = p; p += (size_t)N * 4;
    float* g    = p; p += (size_t)N * 8;
    float* as2  = p; p += (size_t)N;
    float* ad2  = p; p += (size_t)N;
    int* deg    = (int*)p; p += (size_t)N;
    int* rowptr = (int*)p; p += (size_t)N + 1;
    int* bsum   = (int*)p; p += ((size_t)N + 255) / 256;
    int* rank   = (int*)p; p += (size_t)total;
    int* csr    = (int*)p; p += (size_t)total;

    const int eb = (total + 255) / 256;
    const int nb = (N + 255) / 256;

    hipMemsetAsync(deg, 0, (size_t)N * sizeof(int), stream);
    // fused: rank pass + layer-1 GEMM
    gemm1_k<<<(N + 63) / 64, 256, 0, stream>>>(x, W1, as1w, ad1w, h1b, as1, ad1, N,
                                               ei, E, deg, rank);
    blocksum_k<<<nb, 256, 0, stream>>>(deg, N, bsum);
    scanbsum_k<<<1, 1024, 0, stream>>>(bsum, nb);
    rowptr_k<<<nb, 256, 0, stream>>>(deg, bsum, N, E, rowptr);
    place_k<<<eb, 256, 0, stream>>>(ei, E, N, rank, rowptr, csr);

    // layer 1: softmax + aggregate + bias + ELU + gemm2 + attn2 dots (fused)
    gat1_k<<<(N * 64 + 255) / 256, 256, 0, stream>>>(csr, rowptr, as1, ad1, h1b, b1,
                                                     W2, as2w, ad2w, g, as2, ad2, N);
    // layer 2 + epilogue
    gat2_k<<<(N * 64 + 255) / 256, 256, 0, stream>>>(csr, rowptr, as2, ad2, g, b2v, Wlin, blin,
                                                     (float*)d_out, N);
}

// Round 9
// 439.035 us; speedup vs baseline: 4.4473x; 1.0182x over previous
//
#include <hip/hip_runtime.h>
#include <hip/hip_bf16.h>

__device__ __forceinline__ float lrelu02(float v) { return v > 0.f ? v : 0.2f * v; }

// manual bf16 <-> f32 (RNE); finite data only
__device__ __forceinline__ float bf2f(unsigned short u) {
    union { unsigned int i; float f; } v; v.i = ((unsigned int)u) << 16; return v.f;
}
__device__ __forceinline__ unsigned short f2bf(float f) {
    union { float f; unsigned int i; } v; v.f = f;
    unsigned int x = v.i;
    return (unsigned short)((x + 0x7fffu + ((x >> 16) & 1u)) >> 16);
}
// packed-pair bf16 extract
__device__ __forceinline__ float blo(unsigned int u) {
    union { unsigned int i; float f; } v; v.i = u << 16; return v.f;
}
__device__ __forceinline__ float bhi(unsigned int u) {
    union { unsigned int i; float f; } v; v.i = u & 0xffff0000u; return v.f;
}

// ---------- fused: CSR rank pass + layer-1 dense (h1 = x @ W1 + attn dots) ----------
// W staged in LDS as packed bf16 (32 KB): 2x occupancy vs fp32 (4-5 blocks/CU), and the
// per-k ds_read_b128 at byte offset 256k+16*cl starts at bank 4cl%32 -> 2-way = free
// (the fp32 layout was 4-way conflicted: 6.4M conflict cycles in r8 profile).
__global__ __launch_bounds__(256) void gemm1_k(
    const float* __restrict__ x, const float* __restrict__ W1,
    const float* __restrict__ aw_s, const float* __restrict__ aw_d,
    unsigned short* __restrict__ h1b, float* __restrict__ as1, float* __restrict__ ad1, int N,
    const int* __restrict__ ei, int E, int* __restrict__ deg, int* __restrict__ rank)
{
    // --- rank slice (grid-stride over E+N edges); hides under the GEMM's FMA stream ---
    {
        const int total = E + N;
        const int stride = gridDim.x * 256;
        for (int e = blockIdx.x * 256 + threadIdx.x; e < total; e += stride) {
            int d = (e < E) ? ei[E + e] : (e - E);
            rank[e] = atomicAdd(&deg[d], 1);
        }
    }

    // --- stage W1 as packed bf16: Wl[k*64 + j] holds cols {2j, 2j+1} of row k ---
    __shared__ unsigned int Wl[128 * 64];   // 32 KB
    {
        const float4* W4 = (const float4*)W1;
        for (int i = threadIdx.x; i < 128 * 32; i += 256) {
            float4 f = W4[i];                       // row k = i>>5, cols 4t..4t+3 (t = i&31)
            unsigned int lo = f2bf(f.x) | ((unsigned)f2bf(f.y) << 16);
            unsigned int hi = f2bf(f.z) | ((unsigned)f2bf(f.w) << 16);
            int k = i >> 5, t = i & 31;
            Wl[k * 64 + 2 * t]     = lo;
            Wl[k * 64 + 2 * t + 1] = hi;
        }
    }

    const int cl = threadIdx.x & 15;
    const int rg = threadIdx.x >> 4;
    const int head = cl >> 2;
    const int row0 = blockIdx.x * 64 + rg * 4;
    __syncthreads();

    const float4* x4[4];
    bool rv[4];
    #pragma unroll
    for (int r = 0; r < 4; ++r) {
        int rr = row0 + r;
        rv[r] = rr < N;
        int rc = rv[r] ? rr : (N - 1);
        x4[r] = (const float4*)(x + (size_t)rc * 128);
    }

    float acc[4][8];
    #pragma unroll
    for (int r = 0; r < 4; ++r)
        #pragma unroll
        for (int c = 0; c < 8; ++c) acc[r][c] = 0.f;

    for (int k4 = 0; k4 < 32; ++k4) {
        float4 xv[4];
        #pragma unroll
        for (int r = 0; r < 4; ++r) xv[r] = x4[r][k4];
        #pragma unroll
        for (int kk = 0; kk < 4; ++kk) {
            const int k = k4 * 4 + kk;
            const uint4 wp = *(const uint4*)(Wl + k * 64 + cl * 4);  // 8 cols, one b128
            const float w0 = blo(wp.x), w1 = bhi(wp.x);
            const float w2 = blo(wp.y), w3 = bhi(wp.y);
            const float w4 = blo(wp.z), w5 = bhi(wp.z);
            const float w6 = blo(wp.w), w7 = bhi(wp.w);
            #pragma unroll
            for (int r = 0; r < 4; ++r) {
                const float xk = kk == 0 ? xv[r].x : kk == 1 ? xv[r].y : kk == 2 ? xv[r].z : xv[r].w;
                acc[r][0] = fmaf(xk, w0, acc[r][0]);
                acc[r][1] = fmaf(xk, w1, acc[r][1]);
                acc[r][2] = fmaf(xk, w2, acc[r][2]);
                acc[r][3] = fmaf(xk, w3, acc[r][3]);
                acc[r][4] = fmaf(xk, w4, acc[r][4]);
                acc[r][5] = fmaf(xk, w5, acc[r][5]);
                acc[r][6] = fmaf(xk, w6, acc[r][6]);
                acc[r][7] = fmaf(xk, w7, acc[r][7]);
            }
        }
    }

    float ws_[8], wd_[8];
    #pragma unroll
    for (int c = 0; c < 8; ++c) { ws_[c] = aw_s[cl * 8 + c]; wd_[c] = aw_d[cl * 8 + c]; }

    #pragma unroll
    for (int r = 0; r < 4; ++r) {
        float s = 0.f, d = 0.f;
        #pragma unroll
        for (int c = 0; c < 8; ++c) { s = fmaf(acc[r][c], ws_[c], s); d = fmaf(acc[r][c], wd_[c], d); }
        s += __shfl_xor(s, 1); s += __shfl_xor(s, 2);
        d += __shfl_xor(d, 1); d += __shfl_xor(d, 2);
        if (rv[r]) {
            if ((cl & 3) == 0) { as1[(row0 + r) * 4 + head] = s; ad1[(row0 + r) * 4 + head] = d; }
            uint4 pk;
            pk.x = f2bf(acc[r][0]) | ((unsigned)f2bf(acc[r][1]) << 16);
            pk.y = f2bf(acc[r][2]) | ((unsigned)f2bf(acc[r][3]) << 16);
            pk.z = f2bf(acc[r][4]) | ((unsigned)f2bf(acc[r][5]) << 16);
            pk.w = f2bf(acc[r][6]) | ((unsigned)f2bf(acc[r][7]) << 16);
            *(uint4*)(h1b + (size_t)(row0 + r) * 128 + cl * 8) = pk;
        }
    }
}

// ---------- CSR scan ----------
__global__ __launch_bounds__(256) void blocksum_k(
    const int* __restrict__ deg, int N, int* __restrict__ bsum)
{
    __shared__ int sh[256];
    int i = blockIdx.x * 256 + threadIdx.x;
    sh[threadIdx.x] = (i < N) ? deg[i] : 0;
    __syncthreads();
    for (int off = 128; off; off >>= 1) {
        if (threadIdx.x < off) sh[threadIdx.x] += sh[threadIdx.x + off];
        __syncthreads();
    }
    if (threadIdx.x == 0) bsum[blockIdx.x] = sh[0];
}

__global__ __launch_bounds__(1024) void scanbsum_k(int* __restrict__ bsum, int nb)
{
    __shared__ int buf[1024];
    __shared__ int carry;
    if (threadIdx.x == 0) carry = 0;
    __syncthreads();
    for (int base = 0; base < nb; base += 1024) {
        int i = base + threadIdx.x;
        int v = (i < nb) ? bsum[i] : 0;
        buf[threadIdx.x] = v;
        __syncthreads();
        for (int off = 1; off < 1024; off <<= 1) {
            int t = (threadIdx.x >= off) ? buf[threadIdx.x - off] : 0;
            __syncthreads();
            buf[threadIdx.x] += t;
            __syncthreads();
        }
        if (i < nb) bsum[i] = buf[threadIdx.x] - v + carry;   // exclusive
        __syncthreads();
        if (threadIdx.x == 0) carry += buf[1023];
        __syncthreads();
    }
}

__global__ __launch_bounds__(256) void rowptr_k(
    const int* __restrict__ deg, const int* __restrict__ bsum, int N, int E,
    int* __restrict__ rowptr)
{
    __shared__ int buf[256];
    int i = blockIdx.x * 256 + threadIdx.x;
    int v = (i < N) ? deg[i] : 0;
    buf[threadIdx.x] = v;
    __syncthreads();
    for (int off = 1; off < 256; off <<= 1) {
        int t = (threadIdx.x >= off) ? buf[threadIdx.x - off] : 0;
        __syncthreads();
        buf[threadIdx.x] += t;
        __syncthreads();
    }
    if (i < N) rowptr[i] = bsum[blockIdx.x] + buf[threadIdx.x] - v;
    if (i == 0) rowptr[N] = E + N;
}

// Pure scatter, no atomic (rank already known).
__global__ __launch_bounds__(256) void place_k(
    const int* __restrict__ ei, int E, int N,
    const int* __restrict__ rank, const int* __restrict__ rowptr,
    int* __restrict__ csr)
{
    int e = blockIdx.x * 256 + threadIdx.x;
    if (e >= E + N) return;
    int s, d;
    if (e < E) { s = ei[e]; d = ei[E + e]; } else { s = d = e - E; }
    csr[rowptr[d] + rank[e]] = s;
}

// ---------- layer-1 fused: softmax-aggregate + bias + ELU + gemm2 + attn2 dots ----------
__global__ __launch_bounds__(256) void gat1_k(
    const int* __restrict__ csr, const int* __restrict__ rowptr,
    const float* __restrict__ as1, const float* __restrict__ ad1,
    const unsigned short* __restrict__ h1b, const float* __restrict__ b1,
    const float* __restrict__ W2, const float* __restrict__ aw_s2, const float* __restrict__ aw_d2,
    float* __restrict__ g, float* __restrict__ as2, float* __restrict__ ad2, int N)
{
    __shared__ float red[4][8][12];   // [wave][src-lane][j]
    const int wv   = threadIdx.x >> 6;
    const int wid  = (blockIdx.x * 256 + threadIdx.x) >> 6;
    const int lane = threadIdx.x & 63;
    if (wid >= N) return;
    const int start = rowptr[wid], end = rowptr[wid + 1];
    const int i16 = lane & 15;
    const int hh  = lane >> 4;
    const float adh = ad1[wid * 4 + hh];
    const float mh  = lrelu02(as1[wid * 4 + hh] + adh);   // self-logit offset (den >= 1)
    const unsigned short* hb = h1b + lane * 2;

    float den = 0.f, acc0 = 0.f, acc1 = 0.f;
    int k0 = start;
    for (; k0 + 16 <= end; k0 += 16) {
        int s = csr[k0 + i16];
        float w = __expf(lrelu02(as1[s * 4 + hh] + adh) - mh);
        den += w;
        #pragma unroll
        for (int e = 0; e < 16; ++e) {
            int se = __builtin_amdgcn_readlane(s, e);
            float we = __shfl(w, e, 16);
            unsigned int pv = *(const unsigned int*)(hb + (size_t)se * 128);
            acc0 = fmaf(bf2f((unsigned short)pv), we, acc0);
            acc1 = fmaf(bf2f((unsigned short)(pv >> 16)), we, acc1);
        }
    }
    int cnt = end - k0;
    if (cnt > 0) {
        int s = (i16 < cnt) ? csr[k0 + i16] : wid;
        float w = (i16 < cnt) ? __expf(lrelu02(as1[s * 4 + hh] + adh) - mh) : 0.f;
        den += w;
        for (int e = 0; e < cnt; ++e) {
            int se = __builtin_amdgcn_readlane(s, e);
            float we = __shfl(w, e, 16);
            unsigned int pv = *(const unsigned int*)(hb + (size_t)se * 128);
            acc0 = fmaf(bf2f((unsigned short)pv), we, acc0);
            acc1 = fmaf(bf2f((unsigned short)(pv >> 16)), we, acc1);
        }
    }
    den += __shfl_xor(den, 1); den += __shfl_xor(den, 2);
    den += __shfl_xor(den, 4); den += __shfl_xor(den, 8);
    const float rden = 1.f / (den + 1e-16f);
    float v0 = acc0 * rden + b1[lane * 2];
    float v1 = acc1 * rden + b1[lane * 2 + 1];
    v0 = v0 > 0.f ? v0 : expm1f(v0);
    v1 = v1 > 0.f ? v1 : expm1f(v1);

    // --- fused gemm2: g_j = sum_k elu_out[k] * W2[k][j] (k = 2*lane, 2*lane+1) ---
    const float4 a0 = *(const float4*)(W2 + 16 * lane);
    const float4 a1 = *(const float4*)(W2 + 16 * lane + 4);
    const float4 b0 = *(const float4*)(W2 + 16 * lane + 8);
    const float4 b1v = *(const float4*)(W2 + 16 * lane + 12);
    float p[8];
    p[0] = v0 * a0.x + v1 * b0.x;  p[1] = v0 * a0.y + v1 * b0.y;
    p[2] = v0 * a0.z + v1 * b0.z;  p[3] = v0 * a0.w + v1 * b0.w;
    p[4] = v0 * a1.x + v1 * b1v.x; p[5] = v0 * a1.y + v1 * b1v.y;
    p[6] = v0 * a1.z + v1 * b1v.z; p[7] = v0 * a1.w + v1 * b1v.w;
    #pragma unroll
    for (int j = 0; j < 8; ++j) {
        p[j] += __shfl_xor(p[j], 8);
        p[j] += __shfl_xor(p[j], 16);
        p[j] += __shfl_xor(p[j], 32);
    }
    if (lane < 8) {
        #pragma unroll
        for (int j = 0; j < 8; ++j) red[wv][lane][j] = p[j];
    }
    if (lane < 8) {
        float gj = 0.f;
        #pragma unroll
        for (int c = 0; c < 8; ++c) gj += red[wv][c][lane];
        g[(size_t)wid * 8 + lane] = gj;
        float ts = gj * aw_s2[lane], td = gj * aw_d2[lane];
        ts += __shfl_xor(ts, 1); ts += __shfl_xor(ts, 2); ts += __shfl_xor(ts, 4);
        td += __shfl_xor(td, 1); td += __shfl_xor(td, 2); td += __shfl_xor(td, 4);
        if (lane == 0) { as2[wid] = ts; ad2[wid] = td; }
    }
}

// ---------- layer-2 single-pass softmax+aggregate+epilogue: one wave per dst ----------
__global__ __launch_bounds__(256) void gat2_k(
    const int* __restrict__ csr, const int* __restrict__ rowptr,
    const float* __restrict__ as2, const float* __restrict__ ad2,
    const float* __restrict__ g, const float* __restrict__ b2_,
    const float* __restrict__ Wlin, const float* __restrict__ blin,
    float* __restrict__ out, int N)
{
    const int wid  = (blockIdx.x * 256 + threadIdx.x) >> 6;
    const int lane = threadIdx.x & 63;
    if (wid >= N) return;
    const int start = rowptr[wid], end = rowptr[wid + 1];
    const int i8  = lane & 7;
    const int grp = lane >> 3;
    const float adh = ad2[wid];
    const float mh  = lrelu02(as2[wid] + adh);
    float den = 0.f, acc = 0.f;
    int k0 = start;
    for (; k0 + 8 <= end; k0 += 8) {
        int s = csr[k0 + i8];
        float w = __expf(lrelu02(as2[s] + adh) - mh);
        den += w;
        int   se = __shfl(s, grp, 8);
        float we = __shfl(w, grp, 8);
        acc = fmaf(we, g[(size_t)se * 8 + i8], acc);
    }
    int cnt = end - k0;
    if (cnt > 0) {
        int s = (i8 < cnt) ? csr[k0 + i8] : wid;
        float w = (i8 < cnt) ? __expf(lrelu02(as2[s] + adh) - mh) : 0.f;
        den += w;
        int   se = __shfl(s, grp, 8);
        float we = __shfl(w, grp, 8);
        acc = fmaf(we, g[(size_t)se * 8 + i8], acc);
    }
    den += __shfl_xor(den, 1); den += __shfl_xor(den, 2); den += __shfl_xor(den, 4);
    acc += __shfl_xor(acc, 8); acc += __shfl_xor(acc, 16); acc += __shfl_xor(acc, 32);
    float v = acc / (den + 1e-16f) + b2_[i8];
    v = v > 0.f ? v : expm1f(v);
    float t = v * Wlin[i8];
    t += __shfl_xor(t, 1); t += __shfl_xor(t, 2); t += __shfl_xor(t, 4);
    if (lane == 0) out[wid] = 1.f / (1.f + __expf(-(t + blin[0])));
}

extern "C" void kernel_launch(void* const* d_in, const int* in_sizes, int n_in,
                              void* d_out, int out_size, void* d_ws, size_t ws_size,
                              hipStream_t stream)
{
    (void)n_in; (void)out_size; (void)ws_size;
    const float* x    = (const float*)d_in[0];
    const int*   ei   = (const int*)d_in[1];
    // d_in[2] = edge_attr, ignored
    const float* W1   = (const float*)d_in[3];
    const float* as1w = (const float*)d_in[4];
    const float* ad1w = (const float*)d_in[5];
    const float* b1   = (const float*)d_in[6];
    const float* W2   = (const float*)d_in[7];
    const float* as2w = (const float*)d_in[8];
    const float* ad2w = (const float*)d_in[9];
    const float* b2v  = (const float*)d_in[10];
    const float* Wlin = (const float*)d_in[11];
    const float* blin = (const float*)d_in[12];

    const int N = in_sizes[0] / 128;
    const int E = in_sizes[1] / 2;
    const int total = E + N;

    // workspace layout
    float* p = (float*)d_ws;
    unsigned short* h1b = (unsigned short*)p; p += (size_t)N * 64;  // N*128 bf16
    float* as1  = p; p += (size_t)N * 4;
    float* ad1  = p; p += (size_t)N * 4;
    float* g    = p; p += (size_t)N * 8;
    float* as2  = p; p += (size_t)N;
    float* ad2  = p; p += (size_t)N;
    int* deg    = (int*)p; p += (size_t)N;
    int* rowptr = (int*)p; p += (size_t)N + 1;
    int* bsum   = (int*)p; p += ((size_t)N + 255) / 256;
    int* rank   = (int*)p; p += (size_t)total;
    int* csr    = (int*)p; p += (size_t)total;

    const int eb = (total + 255) / 256;
    const int nb = (N + 255) / 256;

    hipMemsetAsync(deg, 0, (size_t)N * sizeof(int), stream);
    // fused: rank pass + layer-1 GEMM (bf16 W in LDS, 32 KB)
    gemm1_k<<<(N + 63) / 64, 256, 0, stream>>>(x, W1, as1w, ad1w, h1b, as1, ad1, N,
                                               ei, E, deg, rank);
    blocksum_k<<<nb, 256, 0, stream>>>(deg, N, bsum);
    scanbsum_k<<<1, 1024, 0, stream>>>(bsum, nb);
    rowptr_k<<<nb, 256, 0, stream>>>(deg, bsum, N, E, rowptr);
    place_k<<<eb, 256, 0, stream>>>(ei, E, N, rank, rowptr, csr);

    // layer 1: softmax + aggregate + bias + ELU + gemm2 + attn2 dots (fused)
    gat1_k<<<(N * 64 + 255) / 256, 256, 0, stream>>>(csr, rowptr, as1, ad1, h1b, b1,
                                                     W2, as2w, ad2w, g, as2, ad2, N);
    // layer 2 + epilogue
    gat2_k<<<(N * 64 + 255) / 256, 256, 0, stream>>>(csr, rowptr, as2, ad2, g, b2v, Wlin, blin,
                                                     (float*)d_out, N);
}